// Round 1
// baseline (525.268 us; speedup 1.0000x reference)
//
#include <hip/hip_runtime.h>
#include <hip/hip_bf16.h>
#include <stdint.h>

#define BM 128
#define BN 128
#define BK 32

using f32x4   = __attribute__((ext_vector_type(4))) float;
using half8   = __attribute__((ext_vector_type(8))) _Float16;
using float4v = __attribute__((ext_vector_type(4))) float;

typedef const __attribute__((address_space(1))) void gas_void;
typedef __attribute__((address_space(3))) void las_void;

__device__ __forceinline__ void gload_lds16(const void* gptr, void* lptr) {
  __builtin_amdgcn_global_load_lds((gas_void*)(uintptr_t)gptr,
                                   (las_void*)(uintptr_t)lptr, 16, 0, 0);
}

#define MFMA_F16(a, b, c) __builtin_amdgcn_mfma_f32_16x16x32_f16((a), (b), (c), 0, 0, 0)

// -------------------- fp32 -> fp16 convert, 8 elems/thread --------------------
__global__ void k_cvt16(const float* __restrict__ in, _Float16* __restrict__ out, long n8) {
  long i = (long)blockIdx.x * blockDim.x + threadIdx.x;
  if (i >= n8) return;
  const float4v* p = (const float4v*)(in + i * 8);
  float4v a = p[0], b = p[1];
  half8 o;
  o[0] = (_Float16)a[0]; o[1] = (_Float16)a[1]; o[2] = (_Float16)a[2]; o[3] = (_Float16)a[3];
  o[4] = (_Float16)b[0]; o[5] = (_Float16)b[1]; o[6] = (_Float16)b[2]; o[7] = (_Float16)b[3];
  *(half8*)(out + i * 8) = o;
}

// -------------------- bt-GEMM: C[m][n] = sum_k A[m][k]*B[n][k] --------------------
// A row-major [M][K], B row-major [N][K] (i.e. B^T input). 128x128 tile, BK=32,
// 256 threads = 4 waves in 2x2, each wave 64x64 = 4x4 MFMA fragments.
// SMALL_IS_M: which blockIdx axis maps to M-tiles (keep consecutive blocks sharing
// the big operand panel for L2 reuse).
template<bool SMALL_IS_M, bool OUT_F32>
__global__ __launch_bounds__(256)
void k_gemm_bt(const _Float16* __restrict__ A, const _Float16* __restrict__ B,
               void* __restrict__ Cv, const float* __restrict__ bias,
               long M, long N, long K)
{
  __shared__ _Float16 lds[2][2][BM * BK];
  const int tid  = threadIdx.x;
  const int wv   = tid >> 6, lane = tid & 63;
  const int g    = lane >> 4, cidx = lane & 15;
  const long mt  = SMALL_IS_M ? blockIdx.x : blockIdx.y;
  const long nt  = SMALL_IS_M ? blockIdx.y : blockIdx.x;
  const long m0  = mt * BM, n0 = nt * BN;
  const int wr   = wv >> 1, wc = wv & 1;
  const _Float16* Abase = A + m0 * K;
  const _Float16* Bbase = B + n0 * K;
  const int nkt = (int)(K / BK);

  auto stage = [&](int buf, int kt) {
#pragma unroll
    for (int i = 0; i < 2; ++i) {
      const int row = (wv * 2 + i) * 16 + (lane >> 2);
      const int cb  = (lane & 3) * 8;
      const long go = (long)row * K + (long)kt * BK + cb;
      // LDS dest is wave-uniform; HW adds lane*16 (matches linear [row][k] layout)
      gload_lds16(Abase + go, &lds[buf][0][(wv * 2 + i) * 16 * BK]);
      gload_lds16(Bbase + go, &lds[buf][1][(wv * 2 + i) * 16 * BK]);
    }
  };

  f32x4 acc[4][4] = {};
  stage(0, 0);
  __syncthreads();
  for (int kt = 0; kt < nkt; ++kt) {
    const int cur = kt & 1;
    if (kt + 1 < nkt) stage(cur ^ 1, kt + 1);
    const _Float16* la = &lds[cur][0][0];
    const _Float16* lb = &lds[cur][1][0];
    half8 af[4], bf[4];
#pragma unroll
    for (int m = 0; m < 4; ++m)
      af[m] = *(const half8*)&la[(wr * 64 + m * 16 + cidx) * BK + g * 8];
#pragma unroll
    for (int n = 0; n < 4; ++n)
      bf[n] = *(const half8*)&lb[(wc * 64 + n * 16 + cidx) * BK + g * 8];
#pragma unroll
    for (int m = 0; m < 4; ++m)
#pragma unroll
      for (int n = 0; n < 4; ++n)
        acc[m][n] = MFMA_F16(af[m], bf[n], acc[m][n]);
    __syncthreads();
  }

  float bv[4] = {0.f, 0.f, 0.f, 0.f};
  if (bias) {
#pragma unroll
    for (int n = 0; n < 4; ++n) bv[n] = bias[n0 + wc * 64 + n * 16 + cidx];
  }
  if constexpr (OUT_F32) {
    float* C = (float*)Cv;
#pragma unroll
    for (int m = 0; m < 4; ++m)
#pragma unroll
      for (int r = 0; r < 4; ++r) {
        const long row = m0 + wr * 64 + m * 16 + g * 4 + r;
#pragma unroll
        for (int n = 0; n < 4; ++n)
          C[row * N + (n0 + wc * 64 + n * 16 + cidx)] = acc[m][n][r] + bv[n];
      }
  } else {
    _Float16* C = (_Float16*)Cv;
#pragma unroll
    for (int m = 0; m < 4; ++m)
#pragma unroll
      for (int r = 0; r < 4; ++r) {
        const long row = m0 + wr * 64 + m * 16 + g * 4 + r;
#pragma unroll
        for (int n = 0; n < 4; ++n)
          C[row * N + (n0 + wc * 64 + n * 16 + cidx)] = (_Float16)acc[m][n][r];
      }
  }
}

// -------------------- XCA attention core: one block per (b,h) --------------------
// qk: [1536][50176] fp16 channel-major (rows 0..767 = q channels h*48+d, 768.. = k)
// vmat: [50176][768] fp16 token-major; out2: [50176][768] fp16 token-major.
// Phase A: S_qk = q@k^T plus q@q^T / k@k^T diagonals (sumsq for l2-norm) via MFMA,
//          fragments loaded directly from global (no LDS staging needed).
// Softmax in fp32, then Phase B: out = v @ P^T via MFMA (K=48 padded with zero frags).
__global__ __launch_bounds__(256)
void k_xca_attn(const _Float16* __restrict__ qk,
                const _Float16* __restrict__ vmat,
                const float* __restrict__ temperature,
                _Float16* __restrict__ out2)
{
  const int b = blockIdx.x >> 4;
  const int h = blockIdx.x & 15;
  const int tid = threadIdx.x;
  const int w = tid >> 6, lane = tid & 63;
  const int g = lane >> 4, c = lane & 15;
  const long T = 50176;
  const long tb = (long)b * 3136;

  __shared__ float red[4][48 * 48];
  __shared__ float redss[4][2][48];
  __shared__ float inv[2][48];
  __shared__ _Float16 Pb[48 * 48];

  f32x4 sqk[3][3] = {};
  f32x4 sqq[3] = {};
  f32x4 skk[3] = {};

  const _Float16* qbase = qk + (long)(h * 48) * T + tb;
  const _Float16* kbase = qk + (long)(768 + h * 48) * T + tb;

  // ---- Phase A: accumulate S_qk (48x48) + sumsq diagonals over tokens ----
  for (int chunk = w; chunk < 49; chunk += 4) {
    const int t0 = chunk * 64;
    half8 qf[3][2], kf[3][2];
#pragma unroll
    for (int m = 0; m < 3; ++m)
#pragma unroll
      for (int ks = 0; ks < 2; ++ks) {
        const long off = (long)(m * 16 + c) * T + t0 + ks * 32 + g * 8;
        qf[m][ks] = *(const half8*)(qbase + off);
        kf[m][ks] = *(const half8*)(kbase + off);
      }
#pragma unroll
    for (int ks = 0; ks < 2; ++ks)
#pragma unroll
      for (int m = 0; m < 3; ++m) {
        sqq[m] = MFMA_F16(qf[m][ks], qf[m][ks], sqq[m]);
        skk[m] = MFMA_F16(kf[m][ks], kf[m][ks], skk[m]);
#pragma unroll
        for (int n = 0; n < 3; ++n)
          sqk[m][n] = MFMA_F16(qf[m][ks], kf[n][ks], sqk[m][n]);
      }
  }

  // dump per-wave partials
#pragma unroll
  for (int m = 0; m < 3; ++m) {
#pragma unroll
    for (int n = 0; n < 3; ++n)
#pragma unroll
      for (int r = 0; r < 4; ++r)
        red[w][(m * 16 + g * 4 + r) * 48 + n * 16 + c] = sqk[m][n][r];
#pragma unroll
    for (int r = 0; r < 4; ++r)
      if (c == g * 4 + r) {   // diagonal element of the (m,m) fragment
        redss[w][0][m * 16 + c] = sqq[m][r];
        redss[w][1][m * 16 + c] = skk[m][r];
      }
  }
  __syncthreads();

  // reduce sumsq -> 1/max(||.||, eps)
  if (tid < 96) {
    const int is_k = tid / 48, d = tid % 48;
    const float s = redss[0][is_k][d] + redss[1][is_k][d] + redss[2][is_k][d] + redss[3][is_k][d];
    inv[is_k][d] = 1.0f / fmaxf(sqrtf(s), 1e-12f);
  }
  __syncthreads();

  // scale + softmax (rows of 48); one thread per row
  if (tid < 48) {
    const int d = tid;
    const float iq = inv[0][d] * temperature[h];
    float rowv[48];
    float mx = -3.0e38f;
#pragma unroll
    for (int e = 0; e < 48; ++e) {
      const int idx = d * 48 + e;
      float t = (red[0][idx] + red[1][idx] + red[2][idx] + red[3][idx]) * iq * inv[1][e];
      rowv[e] = t;
      mx = fmaxf(mx, t);
    }
    float sum = 0.f;
#pragma unroll
    for (int e = 0; e < 48; ++e) {
      const float p = __expf(rowv[e] - mx);
      rowv[e] = p;
      sum += p;
    }
    const float is = 1.0f / sum;
#pragma unroll
    for (int e = 0; e < 48; ++e)
      Pb[d * 48 + e] = (_Float16)(rowv[e] * is);
  }
  __syncthreads();

  // ---- Phase B: out[t][d] = sum_e v[t][e] * P[d][e] ----
  half8 hz;
#pragma unroll
  for (int j = 0; j < 8; ++j) hz[j] = (_Float16)0.f;

  half8 pf[3][2];
#pragma unroll
  for (int n = 0; n < 3; ++n)
#pragma unroll
    for (int ks = 0; ks < 2; ++ks) {
      const int e = ks * 32 + g * 8;
      pf[n][ks] = (e < 48) ? *(const half8*)&Pb[(n * 16 + c) * 48 + e] : hz;
    }

  const _Float16* vbase = vmat + tb * 768 + h * 48;
  _Float16* obase = out2 + tb * 768 + h * 48;

  for (int chunk = w; chunk < 49; chunk += 4) {
    const int t0 = chunk * 64;
    half8 vf[4][2];
#pragma unroll
    for (int m = 0; m < 4; ++m)
#pragma unroll
      for (int ks = 0; ks < 2; ++ks) {
        const int e = ks * 32 + g * 8;
        vf[m][ks] = (e < 48) ? *(const half8*)(vbase + (long)(t0 + m * 16 + c) * 768 + e) : hz;
      }
    f32x4 acc[4][3];
#pragma unroll
    for (int m = 0; m < 4; ++m)
#pragma unroll
      for (int n = 0; n < 3; ++n) {
        f32x4 z = {0.f, 0.f, 0.f, 0.f};
        acc[m][n] = z;
      }
#pragma unroll
    for (int ks = 0; ks < 2; ++ks)
#pragma unroll
      for (int m = 0; m < 4; ++m)
#pragma unroll
        for (int n = 0; n < 3; ++n)
          acc[m][n] = MFMA_F16(vf[m][ks], pf[n][ks], acc[m][n]);
#pragma unroll
    for (int m = 0; m < 4; ++m)
#pragma unroll
      for (int r = 0; r < 4; ++r) {
        const long t = t0 + m * 16 + g * 4 + r;
#pragma unroll
        for (int n = 0; n < 3; ++n)
          obase[t * 768 + n * 16 + c] = (_Float16)acc[m][n][r];
      }
  }
}

// -------------------- launch --------------------
extern "C" void kernel_launch(void* const* d_in, const int* in_sizes, int n_in,
                              void* d_out, int out_size, void* d_ws, size_t ws_size,
                              hipStream_t stream)
{
  (void)in_sizes; (void)n_in; (void)out_size; (void)ws_size;
  const float* x      = (const float*)d_in[0];
  const float* w_qkv  = (const float*)d_in[1];
  const float* temp   = (const float*)d_in[2];
  const float* w_proj = (const float*)d_in[3];
  const float* b_proj = (const float*)d_in[4];
  float* out = (float*)d_out;

  // workspace layout (bytes), total 312,999,936:
  //   [0)            x16   : 77,070,336  (reused as out2 after gemm1b)
  //   [77070336)     qkbuf : 154,140,672 ([1536][50176] fp16, q/k channel-major)
  //   [231211008)    vbuf  : 77,070,336  ([50176][768] fp16, v token-major)
  //   [308281344)    w16   : 3,538,944   (w_qkv fp16)
  //   [311820288)    wp16  : 1,179,648   (w_proj fp16)
  char* ws = (char*)d_ws;
  _Float16* x16   = (_Float16*)(ws);
  _Float16* qkbuf = (_Float16*)(ws + 77070336L);
  _Float16* vbuf  = (_Float16*)(ws + 231211008L);
  _Float16* w16   = (_Float16*)(ws + 308281344L);
  _Float16* wp16  = (_Float16*)(ws + 311820288L);
  _Float16* out2  = x16;  // safe: x16 consumed before attention writes out2

  k_cvt16<<<18816, 256, 0, stream>>>(x, x16, 4816896L);
  k_cvt16<<<864,   256, 0, stream>>>(w_qkv, w16, 221184L);
  k_cvt16<<<288,   256, 0, stream>>>(w_proj, wp16, 73728L);
  // qk[c][t] = w_qkv[c,:] . x[t,:]  (c in [0,1536))
  k_gemm_bt<true,  false><<<dim3(12, 392), 256, 0, stream>>>(w16, x16, qkbuf, nullptr,
                                                             1536, 50176, 768);
  // v[t][c] = x[t,:] . w_qkv[1536+c,:]
  k_gemm_bt<false, false><<<dim3(6, 392), 256, 0, stream>>>(x16, w16 + 1536L * 768, vbuf, nullptr,
                                                            50176, 768, 768);
  k_xca_attn<<<256, 256, 0, stream>>>(qkbuf, vbuf, temp, out2);
  // out[t][c] = out2[t,:] . w_proj[c,:] + b_proj[c]   (fp32 output)
  k_gemm_bt<false, true ><<<dim3(6, 392), 256, 0, stream>>>(out2, wp16, out, b_proj,
                                                            50176, 768, 768);
}

// Round 2
// 486.937 us; speedup vs baseline: 1.0787x; 1.0787x over previous
//
#include <hip/hip_runtime.h>
#include <hip/hip_bf16.h>
#include <stdint.h>

using f32x4   = __attribute__((ext_vector_type(4))) float;
using half8   = __attribute__((ext_vector_type(8))) _Float16;
using float4v = __attribute__((ext_vector_type(4))) float;

typedef const __attribute__((address_space(1))) void gas_void;
typedef __attribute__((address_space(3))) void las_void;

__device__ __forceinline__ void gload_lds16(const void* gptr, void* lptr) {
  __builtin_amdgcn_global_load_lds((gas_void*)(uintptr_t)gptr,
                                   (las_void*)(uintptr_t)lptr, 16, 0, 0);
}

#define MFMA_F16(a, b, c) __builtin_amdgcn_mfma_f32_16x16x32_f16((a), (b), (c), 0, 0, 0)

// -------------------- fp32 -> fp16 convert, 8 elems/thread --------------------
__global__ void k_cvt16(const float* __restrict__ in, _Float16* __restrict__ out, long n8) {
  long i = (long)blockIdx.x * blockDim.x + threadIdx.x;
  if (i >= n8) return;
  const float4v* p = (const float4v*)(in + i * 8);
  float4v a = p[0], b = p[1];
  half8 o;
  o[0] = (_Float16)a[0]; o[1] = (_Float16)a[1]; o[2] = (_Float16)a[2]; o[3] = (_Float16)a[3];
  o[4] = (_Float16)b[0]; o[5] = (_Float16)b[1]; o[6] = (_Float16)b[2]; o[7] = (_Float16)b[3];
  *(half8*)(out + i * 8) = o;
}

// ==================== 256x256 deep-pipelined bt-GEMM ====================
// C[m][n] = sum_k A[m][k] * B[n][k]; A:[M][K], B:[N][K] row-major fp16.
// 512 threads = 8 waves (2 Mwaves x 4 Nwaves), per-wave 128x64 output.
// BK=32; LDS ring of 4 K-tile slots (A+B, 128 KiB total); staging runs 3
// K-tiles ahead; boundary s_waitcnt vmcnt(8) never drains the pipe.
// LDS bank swizzle: linear granule gi stored at gi ^ ((row>>1)&3) (16B units)
// via pre-swizzled global source (global_load_lds dest must stay linear);
// ds_read applies the same XOR. Requires: M%256==0, N%256==0, K%32==0,
// (K/32)%4==0, K/32 >= 4.
template<bool OUT_F32>
__global__ __launch_bounds__(512, 2)
void k_gemm256(const _Float16* __restrict__ A, const _Float16* __restrict__ B,
               void* __restrict__ Cv, const float* __restrict__ bias,
               long M, long N, long K)
{
  __shared__ _Float16 lds[4 * 2 * 8192];  // 4 slots x (A 256x32 + B 256x32) = 128 KiB
  const int tid  = threadIdx.x;
  const int wv   = tid >> 6, lane = tid & 63;
  const int g    = lane >> 4, cidx = lane & 15;
  const int wr   = wv >> 2, wc = wv & 3;

  // bijective XCD swizzle (m204): each XCD gets a contiguous chunk of wg-space
  const int nwg = (int)gridDim.x;
  const int q = nwg >> 3, r = nwg & 7;
  const int xcd = (int)blockIdx.x & 7, bidx = (int)blockIdx.x >> 3;
  const int wg  = (xcd < r ? xcd * (q + 1) : r * (q + 1) + (xcd - r) * q) + bidx;
  const int mtiles = (int)(M >> 8);
  const long mt = wg % mtiles, nt = wg / mtiles;
  const long m0 = mt * 256, n0 = nt * 256;

  const int nkt = (int)(K >> 5);  // K-tiles of 32

  const _Float16* Ab = A + m0 * K;
  const _Float16* Bb = B + n0 * K;

  // staging: per half (A or B) 2 rounds; round l: wave wv covers chunk l*8+wv
  // (1024 B = 16 rows of 64 B); lane ln -> row chunk*16 + (ln>>2),
  // swizzled source granule (ln&3)^((ln>>3)&3).
  const int srow = lane >> 2;
  const int sgr  = (lane & 3) ^ ((lane >> 3) & 3);

  auto stageA = [&](int slot, int st) {
#pragma unroll
    for (int l = 0; l < 2; ++l) {
      const int chunk = l * 8 + wv;
      const long row = chunk * 16 + srow;
      gload_lds16(Ab + row * K + (long)st * 32 + sgr * 8,
                  &lds[slot * 8192 + chunk * 512]);
    }
  };
  auto stageB = [&](int slot, int st) {
#pragma unroll
    for (int l = 0; l < 2; ++l) {
      const int chunk = l * 8 + wv;
      const long row = chunk * 16 + srow;
      gload_lds16(Bb + row * K + (long)st * 32 + sgr * 8,
                  &lds[32768 + slot * 8192 + chunk * 512]);
    }
  };

  // fragment-read swizzle XOR (fp16 units); same for A and B rows
  const int xo = (g ^ ((cidx >> 1) & 3)) << 3;

  f32x4 acc[8][4] = {};

  // ---- prologue: stage K-tiles 0,1,2; wait tile 0 (12 issued, vmcnt(8)) ----
  stageA(0, 0); stageB(0, 0);
  stageA(1, 1); stageB(1, 1);
  stageA(2, 2); stageB(2, 2);
  asm volatile("s_waitcnt vmcnt(8)" ::: "memory");
  __builtin_amdgcn_sched_barrier(0);
  __builtin_amdgcn_s_barrier();

  for (int kt = 0; kt < nkt; ++kt) {
    const int slot = kt & 3;
    int st = kt + 3; if (st >= nkt) st -= nkt;   // wrapped tail re-stage (harmless)
    const int sslot = st & 3;
    const _Float16* la = &lds[slot * 8192];
    const _Float16* lb = &lds[32768 + slot * 8192];

    half8 af[8], bf[4];
    // ---------------- phase 0 ----------------
#pragma unroll
    for (int m = 0; m < 4; ++m)
      af[m] = *(const half8*)&la[(wr * 128 + m * 16 + cidx) * 32 + xo];
#pragma unroll
    for (int n = 0; n < 4; ++n)
      bf[n] = *(const half8*)&lb[(wc * 64 + n * 16 + cidx) * 32 + xo];
    stageA(sslot, st);
    __builtin_amdgcn_s_barrier();
    __builtin_amdgcn_s_setprio(1);
#pragma unroll
    for (int m = 0; m < 4; ++m)
#pragma unroll
      for (int n = 0; n < 4; ++n)
        acc[m][n] = MFMA_F16(af[m], bf[n], acc[m][n]);
    __builtin_amdgcn_s_setprio(0);
    __builtin_amdgcn_s_barrier();
    // ---------------- phase 1 ----------------
#pragma unroll
    for (int m = 4; m < 8; ++m)
      af[m] = *(const half8*)&la[(wr * 128 + m * 16 + cidx) * 32 + xo];
    stageB(sslot, st);
    __builtin_amdgcn_s_barrier();
    __builtin_amdgcn_s_setprio(1);
#pragma unroll
    for (int m = 4; m < 8; ++m)
#pragma unroll
      for (int n = 0; n < 4; ++n)
        acc[m][n] = MFMA_F16(af[m], bf[n], acc[m][n]);
    __builtin_amdgcn_s_setprio(0);
    // ---- K-tile boundary: counted wait, never drain ----
    asm volatile("s_waitcnt vmcnt(8)" ::: "memory");
    __builtin_amdgcn_sched_barrier(0);
    __builtin_amdgcn_s_barrier();
  }

  // ---------------- epilogue ----------------
  float bv[4] = {0.f, 0.f, 0.f, 0.f};
  if (bias) {
#pragma unroll
    for (int n = 0; n < 4; ++n) bv[n] = bias[n0 + wc * 64 + n * 16 + cidx];
  }
  if constexpr (OUT_F32) {
    float* C = (float*)Cv;
#pragma unroll
    for (int m = 0; m < 8; ++m)
#pragma unroll
      for (int rr = 0; rr < 4; ++rr) {
        const long row = m0 + wr * 128 + m * 16 + g * 4 + rr;
#pragma unroll
        for (int n = 0; n < 4; ++n)
          C[row * N + (n0 + wc * 64 + n * 16 + cidx)] = acc[m][n][rr] + bv[n];
      }
  } else {
    _Float16* C = (_Float16*)Cv;
#pragma unroll
    for (int m = 0; m < 8; ++m)
#pragma unroll
      for (int rr = 0; rr < 4; ++rr) {
        const long row = m0 + wr * 128 + m * 16 + g * 4 + rr;
#pragma unroll
        for (int n = 0; n < 4; ++n)
          C[row * N + (n0 + wc * 64 + n * 16 + cidx)] = (_Float16)acc[m][n][rr];
      }
  }
}

// -------------------- XCA attention core: one block per (b,h) --------------------
__global__ __launch_bounds__(256)
void k_xca_attn(const _Float16* __restrict__ qk,
                const _Float16* __restrict__ vmat,
                const float* __restrict__ temperature,
                _Float16* __restrict__ out2)
{
  const int b = blockIdx.x >> 4;
  const int h = blockIdx.x & 15;
  const int tid = threadIdx.x;
  const int w = tid >> 6, lane = tid & 63;
  const int g = lane >> 4, c = lane & 15;
  const long T = 50176;
  const long tb = (long)b * 3136;

  __shared__ float red[4][48 * 48];
  __shared__ float redss[4][2][48];
  __shared__ float inv[2][48];
  __shared__ _Float16 Pb[48 * 48];

  f32x4 sqk[3][3] = {};
  f32x4 sqq[3] = {};
  f32x4 skk[3] = {};

  const _Float16* qbase = qk + (long)(h * 48) * T + tb;
  const _Float16* kbase = qk + (long)(768 + h * 48) * T + tb;

  for (int chunk = w; chunk < 49; chunk += 4) {
    const int t0 = chunk * 64;
    half8 qf[3][2], kf[3][2];
#pragma unroll
    for (int m = 0; m < 3; ++m)
#pragma unroll
      for (int ks = 0; ks < 2; ++ks) {
        const long off = (long)(m * 16 + c) * T + t0 + ks * 32 + g * 8;
        qf[m][ks] = *(const half8*)(qbase + off);
        kf[m][ks] = *(const half8*)(kbase + off);
      }
#pragma unroll
    for (int ks = 0; ks < 2; ++ks)
#pragma unroll
      for (int m = 0; m < 3; ++m) {
        sqq[m] = MFMA_F16(qf[m][ks], qf[m][ks], sqq[m]);
        skk[m] = MFMA_F16(kf[m][ks], kf[m][ks], skk[m]);
#pragma unroll
        for (int n = 0; n < 3; ++n)
          sqk[m][n] = MFMA_F16(qf[m][ks], kf[n][ks], sqk[m][n]);
      }
  }

#pragma unroll
  for (int m = 0; m < 3; ++m) {
#pragma unroll
    for (int n = 0; n < 3; ++n)
#pragma unroll
      for (int r = 0; r < 4; ++r)
        red[w][(m * 16 + g * 4 + r) * 48 + n * 16 + c] = sqk[m][n][r];
#pragma unroll
    for (int r = 0; r < 4; ++r)
      if (c == g * 4 + r) {
        redss[w][0][m * 16 + c] = sqq[m][r];
        redss[w][1][m * 16 + c] = skk[m][r];
      }
  }
  __syncthreads();

  if (tid < 96) {
    const int is_k = tid / 48, d = tid % 48;
    const float s = redss[0][is_k][d] + redss[1][is_k][d] + redss[2][is_k][d] + redss[3][is_k][d];
    inv[is_k][d] = 1.0f / fmaxf(sqrtf(s), 1e-12f);
  }
  __syncthreads();

  if (tid < 48) {
    const int d = tid;
    const float iq = inv[0][d] * temperature[h];
    float rowv[48];
    float mx = -3.0e38f;
#pragma unroll
    for (int e = 0; e < 48; ++e) {
      const int idx = d * 48 + e;
      float t = (red[0][idx] + red[1][idx] + red[2][idx] + red[3][idx]) * iq * inv[1][e];
      rowv[e] = t;
      mx = fmaxf(mx, t);
    }
    float sum = 0.f;
#pragma unroll
    for (int e = 0; e < 48; ++e) {
      const float p = __expf(rowv[e] - mx);
      rowv[e] = p;
      sum += p;
    }
    const float is = 1.0f / sum;
#pragma unroll
    for (int e = 0; e < 48; ++e)
      Pb[d * 48 + e] = (_Float16)(rowv[e] * is);
  }
  __syncthreads();

  half8 hz;
#pragma unroll
  for (int j = 0; j < 8; ++j) hz[j] = (_Float16)0.f;

  half8 pf[3][2];
#pragma unroll
  for (int n = 0; n < 3; ++n)
#pragma unroll
    for (int ks = 0; ks < 2; ++ks) {
      const int e = ks * 32 + g * 8;
      pf[n][ks] = (e < 48) ? *(const half8*)&Pb[(n * 16 + c) * 48 + e] : hz;
    }

  const _Float16* vbase = vmat + tb * 768 + h * 48;
  _Float16* obase = out2 + tb * 768 + h * 48;

  for (int chunk = w; chunk < 49; chunk += 4) {
    const int t0 = chunk * 64;
    half8 vf[4][2];
#pragma unroll
    for (int m = 0; m < 4; ++m)
#pragma unroll
      for (int ks = 0; ks < 2; ++ks) {
        const int e = ks * 32 + g * 8;
        vf[m][ks] = (e < 48) ? *(const half8*)(vbase + (long)(t0 + m * 16 + c) * 768 + e) : hz;
      }
    f32x4 acc[4][3];
#pragma unroll
    for (int m = 0; m < 4; ++m)
#pragma unroll
      for (int n = 0; n < 3; ++n) {
        f32x4 z = {0.f, 0.f, 0.f, 0.f};
        acc[m][n] = z;
      }
#pragma unroll
    for (int ks = 0; ks < 2; ++ks)
#pragma unroll
      for (int m = 0; m < 4; ++m)
#pragma unroll
        for (int n = 0; n < 3; ++n)
          acc[m][n] = MFMA_F16(vf[m][ks], pf[n][ks], acc[m][n]);
#pragma unroll
    for (int m = 0; m < 4; ++m)
#pragma unroll
      for (int r = 0; r < 4; ++r) {
        const long t = t0 + m * 16 + g * 4 + r;
#pragma unroll
        for (int n = 0; n < 3; ++n)
          obase[t * 768 + n * 16 + c] = (_Float16)acc[m][n][r];
      }
  }
}

// -------------------- launch --------------------
extern "C" void kernel_launch(void* const* d_in, const int* in_sizes, int n_in,
                              void* d_out, int out_size, void* d_ws, size_t ws_size,
                              hipStream_t stream)
{
  (void)in_sizes; (void)n_in; (void)out_size; (void)ws_size;
  const float* x      = (const float*)d_in[0];
  const float* w_qkv  = (const float*)d_in[1];
  const float* temp   = (const float*)d_in[2];
  const float* w_proj = (const float*)d_in[3];
  const float* b_proj = (const float*)d_in[4];
  float* out = (float*)d_out;

  char* ws = (char*)d_ws;
  _Float16* x16   = (_Float16*)(ws);
  _Float16* qkbuf = (_Float16*)(ws + 77070336L);
  _Float16* vbuf  = (_Float16*)(ws + 231211008L);
  _Float16* w16   = (_Float16*)(ws + 308281344L);
  _Float16* wp16  = (_Float16*)(ws + 311820288L);
  _Float16* out2  = x16;  // safe: x16 fully consumed before attention writes out2

  k_cvt16<<<18816, 256, 0, stream>>>(x, x16, 4816896L);
  k_cvt16<<<864,   256, 0, stream>>>(w_qkv, w16, 221184L);
  k_cvt16<<<288,   256, 0, stream>>>(w_proj, wp16, 73728L);
  // qk[c][t] = w_qkv[c,:] . x[t,:]  (c in [0,1536)) -> [1536][50176]
  k_gemm256<false><<<1176, 512, 0, stream>>>(w16, x16, qkbuf, nullptr,
                                             1536, 50176, 768);
  // v[t][c] = x[t,:] . w_qkv[1536+c,:] -> [50176][768]
  k_gemm256<false><<<588, 512, 0, stream>>>(x16, w16 + 1536L * 768, vbuf, nullptr,
                                            50176, 768, 768);
  k_xca_attn<<<256, 256, 0, stream>>>(qkbuf, vbuf, temp, out2);
  // out[t][c] = out2[t,:] . w_proj[c,:] + b_proj[c]  (fp32 + bias)
  k_gemm256<true ><<<588, 512, 0, stream>>>(out2, wp16, out, b_proj,
                                            50176, 768, 768);
}

// Round 3
// 479.400 us; speedup vs baseline: 1.0957x; 1.0157x over previous
//
#include <hip/hip_runtime.h>
#include <hip/hip_bf16.h>
#include <stdint.h>

using f32x4   = __attribute__((ext_vector_type(4))) float;
using half8   = __attribute__((ext_vector_type(8))) _Float16;
using float4v = __attribute__((ext_vector_type(4))) float;

typedef const __attribute__((address_space(1))) void gas_void;
typedef __attribute__((address_space(3))) void las_void;

__device__ __forceinline__ void gload_lds16(const void* gptr, void* lptr) {
  __builtin_amdgcn_global_load_lds((gas_void*)(uintptr_t)gptr,
                                   (las_void*)(uintptr_t)lptr, 16, 0, 0);
}

#define MFMA_F16(a, b, c) __builtin_amdgcn_mfma_f32_16x16x32_f16((a), (b), (c), 0, 0, 0)

// -------------------- fp32 -> fp16 convert, 8 elems/thread --------------------
__global__ void k_cvt16(const float* __restrict__ in, _Float16* __restrict__ out, long n8) {
  long i = (long)blockIdx.x * blockDim.x + threadIdx.x;
  if (i >= n8) return;
  const float4v* p = (const float4v*)(in + i * 8);
  float4v a = p[0], b = p[1];
  half8 o;
  o[0] = (_Float16)a[0]; o[1] = (_Float16)a[1]; o[2] = (_Float16)a[2]; o[3] = (_Float16)a[3];
  o[4] = (_Float16)b[0]; o[5] = (_Float16)b[1]; o[6] = (_Float16)b[2]; o[7] = (_Float16)b[3];
  *(half8*)(out + i * 8) = o;
}

// ==================== 256x256 8-phase bt-GEMM (m201-faithful) ====================
// C[m][n] = sum_k A[m][k]*B[n][k]; A:[M][K], B:[N][K] row-major fp16.
// 512 thr = 8 waves (2M x 4N), per-wave 128x64 out, acc[8][4].
// K-tile = 64 (two 32-k halves kh0/kh1); 2 LDS buffers; iter = 2 K-tiles, 8 phases.
// LDS region (f16 units): buf*32768 + op*16384 + kh*8192 + row*32 + granule*8.
// Swizzle: 16B-granule ^= (row>>1)&3  (2-way bank alias = free). Writes land
// linear via global_load_lds; source pre-swizzled with the same involution.
// Stage schedule (iter j; tiles t0=2j buf0, t1=2j+1 buf1; one half/phase):
//  ph1:A-kh1(t1) ph2:B-kh1(t1) ph3:A-kh0(2j+2) ph4:B-kh0(2j+2)+vmcnt(4)
//  ph5:A-kh1(2j+2) ph6:B-kh1(2j+2) ph7:A-kh0(2j+3) ph8:B-kh0(2j+3)+vmcnt(4)
// Every stage issues one phase after its region's last reader's closing barrier;
// every read's producer is forced-landed by a preceding vmcnt(4). Tail wraps
// (re-stages tiles 0,1 — same safety invariants). Requires M,N%256==0, K%128==0.
template<int ID, bool OUT_F32>
__global__ __launch_bounds__(512, 2)
void k_gemm8p(const _Float16* __restrict__ A, const _Float16* __restrict__ B,
              void* __restrict__ Cv, const float* __restrict__ bias,
              long M, long N, long K)
{
  __shared__ _Float16 lds[65536];  // 128 KiB
  const int tid  = threadIdx.x;
  const int wv   = tid >> 6, lane = tid & 63;
  const int g    = lane >> 4, cidx = lane & 15;
  const int wr   = wv >> 2, wc = wv & 3;

  // bijective XCD swizzle (m204)
  const int nwg = (int)gridDim.x;
  const int q = nwg >> 3, r = nwg & 7;
  const int xcd = (int)blockIdx.x & 7, bidx = (int)blockIdx.x >> 3;
  const int wg  = (xcd < r ? xcd * (q + 1) : r * (q + 1) + (xcd - r) * q) + bidx;
  const int mtiles = (int)(M >> 8);
  const long mt = wg % mtiles, nt = wg / mtiles;
  const long m0 = mt * 256, n0 = nt * 256;

  const int NT = (int)(K >> 6);  // K-tiles of 64
  const int NI = NT >> 1;

  const _Float16* Ab = A + m0 * K;
  const _Float16* Bb = B + n0 * K;

  // staging lane constants: chunk = 16 rows x 64B; lane -> row lane>>2, dest
  // granule lane&3; source granule pre-swizzled (l&3)^((l>>3)&3)
  const int srow = lane >> 2;
  const int sgr  = (lane & 3) ^ ((lane >> 3) & 3);

  auto stage = [&](int op, int buf, int kh, int t) {
    const _Float16* src = op ? Bb : Ab;
    const long koff = (long)t * 64 + kh * 32 + sgr * 8;
#pragma unroll
    for (int l = 0; l < 2; ++l) {
      const int chunk = l * 8 + wv;
      gload_lds16(src + (long)(chunk * 16 + srow) * K + koff,
                  &lds[buf * 32768 + op * 16384 + kh * 8192 + chunk * 512]);
    }
  };

  // fragment-read swizzled granule: g ^ ((row>>1)&3) == g ^ ((cidx>>1)&3)
  const int gr  = (g ^ ((cidx >> 1) & 3)) * 8;
  const int raA = (wr * 128 + cidx) * 32 + gr;          // + m*512 + ks*8192 + buf*32768
  const int raB = 16384 + (wc * 64 + cidx) * 32 + gr;   // + n*512 + ks*8192 + buf*32768

  f32x4 acc[8][4] = {};

  // ---- prologue: t0 kh0, t0 kh1, t1 kh0 (12 loads); force t0 landed ----
  stage(0, 0, 0, 0); stage(1, 0, 0, 0);
  stage(0, 0, 1, 0); stage(1, 0, 1, 0);
  stage(0, 1, 0, 1); stage(1, 1, 0, 1);
  asm volatile("s_waitcnt vmcnt(4)" ::: "memory");
  __builtin_amdgcn_sched_barrier(0);
  __builtin_amdgcn_s_barrier();

#define XPHASE(BUF, KS, MLO, READBF, STAGE, BDRY)                              \
  {                                                                            \
    half8 af_[4];                                                              \
    _Pragma("unroll")                                                          \
    for (int mm = 0; mm < 4; ++mm)                                             \
      af_[mm] = *(const half8*)&lds[(BUF)*32768 + (KS)*8192 + raA + ((MLO)+mm)*512]; \
    if (READBF) {                                                              \
      _Pragma("unroll")                                                        \
      for (int nn = 0; nn < 4; ++nn)                                           \
        bf_[nn] = *(const half8*)&lds[(BUF)*32768 + (KS)*8192 + raB + nn*512]; \
    }                                                                          \
    STAGE;                                                                     \
    if (BDRY) {                                                                \
      asm volatile("s_waitcnt vmcnt(4)" ::: "memory");                         \
      __builtin_amdgcn_sched_barrier(0);                                       \
    }                                                                          \
    __builtin_amdgcn_s_barrier();                                              \
    asm volatile("s_waitcnt lgkmcnt(0)" ::: "memory");                         \
    __builtin_amdgcn_s_setprio(1);                                             \
    _Pragma("unroll")                                                          \
    for (int mm = 0; mm < 4; ++mm)                                             \
      _Pragma("unroll")                                                        \
      for (int nn = 0; nn < 4; ++nn)                                           \
        acc[(MLO)+mm][nn] = MFMA_F16(af_[mm], bf_[nn], acc[(MLO)+mm][nn]);     \
    __builtin_amdgcn_s_setprio(0);                                             \
    __builtin_amdgcn_s_barrier();                                              \
  }

  for (int it = 0; it < NI; ++it) {
    const int t1c = 2 * it + 1;
    int tn2 = 2 * it + 2; if (tn2 >= NT) tn2 -= NT;
    int tn3 = 2 * it + 3; if (tn3 >= NT) tn3 -= NT;
    half8 bf_[4];
    XPHASE(0, 0, 0, true,  stage(0, 1, 1, t1c), false)
    XPHASE(0, 0, 4, false, stage(1, 1, 1, t1c), false)
    XPHASE(0, 1, 0, true,  stage(0, 0, 0, tn2), false)
    XPHASE(0, 1, 4, false, stage(1, 0, 0, tn2), true )
    XPHASE(1, 0, 0, true,  stage(0, 0, 1, tn2), false)
    XPHASE(1, 0, 4, false, stage(1, 0, 1, tn2), false)
    XPHASE(1, 1, 0, true,  stage(0, 1, 0, tn3), false)
    XPHASE(1, 1, 4, false, stage(1, 1, 0, tn3), true )
  }
#undef XPHASE

  // ---------------- epilogue ----------------
  float bv[4] = {0.f, 0.f, 0.f, 0.f};
  if (bias) {
#pragma unroll
    for (int n = 0; n < 4; ++n) bv[n] = bias[n0 + wc * 64 + n * 16 + cidx];
  }
  if constexpr (OUT_F32) {
    float* C = (float*)Cv;
#pragma unroll
    for (int m = 0; m < 8; ++m)
#pragma unroll
      for (int rr = 0; rr < 4; ++rr) {
        const long row = m0 + wr * 128 + m * 16 + g * 4 + rr;
#pragma unroll
        for (int n = 0; n < 4; ++n)
          C[row * N + (n0 + wc * 64 + n * 16 + cidx)] = acc[m][n][rr] + bv[n];
      }
  } else {
    _Float16* C = (_Float16*)Cv;
#pragma unroll
    for (int m = 0; m < 8; ++m)
#pragma unroll
      for (int rr = 0; rr < 4; ++rr) {
        const long row = m0 + wr * 128 + m * 16 + g * 4 + rr;
#pragma unroll
        for (int n = 0; n < 4; ++n)
          C[row * N + (n0 + wc * 64 + n * 16 + cidx)] = (_Float16)acc[m][n][rr];
      }
  }
}

// -------------------- XCA attention core: one block per (b,h) --------------------
__global__ __launch_bounds__(256)
void k_xca_attn(const _Float16* __restrict__ qk,
                const _Float16* __restrict__ vmat,
                const float* __restrict__ temperature,
                _Float16* __restrict__ out2)
{
  const int b = blockIdx.x >> 4;
  const int h = blockIdx.x & 15;
  const int tid = threadIdx.x;
  const int w = tid >> 6, lane = tid & 63;
  const int g = lane >> 4, c = lane & 15;
  const long T = 50176;
  const long tb = (long)b * 3136;

  __shared__ float red[4][48 * 48];
  __shared__ float redss[4][2][48];
  __shared__ float inv[2][48];
  __shared__ _Float16 Pb[48 * 48];

  f32x4 sqk[3][3] = {};
  f32x4 sqq[3] = {};
  f32x4 skk[3] = {};

  const _Float16* qbase = qk + (long)(h * 48) * T + tb;
  const _Float16* kbase = qk + (long)(768 + h * 48) * T + tb;

  for (int chunk = w; chunk < 49; chunk += 4) {
    const int t0 = chunk * 64;
    half8 qf[3][2], kf[3][2];
#pragma unroll
    for (int m = 0; m < 3; ++m)
#pragma unroll
      for (int ks = 0; ks < 2; ++ks) {
        const long off = (long)(m * 16 + c) * T + t0 + ks * 32 + g * 8;
        qf[m][ks] = *(const half8*)(qbase + off);
        kf[m][ks] = *(const half8*)(kbase + off);
      }
#pragma unroll
    for (int ks = 0; ks < 2; ++ks)
#pragma unroll
      for (int m = 0; m < 3; ++m) {
        sqq[m] = MFMA_F16(qf[m][ks], qf[m][ks], sqq[m]);
        skk[m] = MFMA_F16(kf[m][ks], kf[m][ks], skk[m]);
#pragma unroll
        for (int n = 0; n < 3; ++n)
          sqk[m][n] = MFMA_F16(qf[m][ks], kf[n][ks], sqk[m][n]);
      }
  }

#pragma unroll
  for (int m = 0; m < 3; ++m) {
#pragma unroll
    for (int n = 0; n < 3; ++n)
#pragma unroll
      for (int r = 0; r < 4; ++r)
        red[w][(m * 16 + g * 4 + r) * 48 + n * 16 + c] = sqk[m][n][r];
#pragma unroll
    for (int r = 0; r < 4; ++r)
      if (c == g * 4 + r) {
        redss[w][0][m * 16 + c] = sqq[m][r];
        redss[w][1][m * 16 + c] = skk[m][r];
      }
  }
  __syncthreads();

  if (tid < 96) {
    const int is_k = tid / 48, d = tid % 48;
    const float s = redss[0][is_k][d] + redss[1][is_k][d] + redss[2][is_k][d] + redss[3][is_k][d];
    inv[is_k][d] = 1.0f / fmaxf(sqrtf(s), 1e-12f);
  }
  __syncthreads();

  if (tid < 48) {
    const int d = tid;
    const float iq = inv[0][d] * temperature[h];
    float rowv[48];
    float mx = -3.0e38f;
#pragma unroll
    for (int e = 0; e < 48; ++e) {
      const int idx = d * 48 + e;
      float t = (red[0][idx] + red[1][idx] + red[2][idx] + red[3][idx]) * iq * inv[1][e];
      rowv[e] = t;
      mx = fmaxf(mx, t);
    }
    float sum = 0.f;
#pragma unroll
    for (int e = 0; e < 48; ++e) {
      const float p = __expf(rowv[e] - mx);
      rowv[e] = p;
      sum += p;
    }
    const float is = 1.0f / sum;
#pragma unroll
    for (int e = 0; e < 48; ++e)
      Pb[d * 48 + e] = (_Float16)(rowv[e] * is);
  }
  __syncthreads();

  half8 hz;
#pragma unroll
  for (int j = 0; j < 8; ++j) hz[j] = (_Float16)0.f;

  half8 pf[3][2];
#pragma unroll
  for (int n = 0; n < 3; ++n)
#pragma unroll
    for (int ks = 0; ks < 2; ++ks) {
      const int e = ks * 32 + g * 8;
      pf[n][ks] = (e < 48) ? *(const half8*)&Pb[(n * 16 + c) * 48 + e] : hz;
    }

  const _Float16* vbase = vmat + tb * 768 + h * 48;
  _Float16* obase = out2 + tb * 768 + h * 48;

  for (int chunk = w; chunk < 49; chunk += 4) {
    const int t0 = chunk * 64;
    half8 vf[4][2];
#pragma unroll
    for (int m = 0; m < 4; ++m)
#pragma unroll
      for (int ks = 0; ks < 2; ++ks) {
        const int e = ks * 32 + g * 8;
        vf[m][ks] = (e < 48) ? *(const half8*)(vbase + (long)(t0 + m * 16 + c) * 768 + e) : hz;
      }
    f32x4 acc[4][3];
#pragma unroll
    for (int m = 0; m < 4; ++m)
#pragma unroll
      for (int n = 0; n < 3; ++n) {
        f32x4 z = {0.f, 0.f, 0.f, 0.f};
        acc[m][n] = z;
      }
#pragma unroll
    for (int ks = 0; ks < 2; ++ks)
#pragma unroll
      for (int m = 0; m < 4; ++m)
#pragma unroll
        for (int n = 0; n < 3; ++n)
          acc[m][n] = MFMA_F16(vf[m][ks], pf[n][ks], acc[m][n]);
#pragma unroll
    for (int m = 0; m < 4; ++m)
#pragma unroll
      for (int r = 0; r < 4; ++r) {
        const long t = t0 + m * 16 + g * 4 + r;
#pragma unroll
        for (int n = 0; n < 3; ++n)
          obase[t * 768 + n * 16 + c] = (_Float16)acc[m][n][r];
      }
  }
}

// -------------------- launch --------------------
extern "C" void kernel_launch(void* const* d_in, const int* in_sizes, int n_in,
                              void* d_out, int out_size, void* d_ws, size_t ws_size,
                              hipStream_t stream)
{
  (void)in_sizes; (void)n_in; (void)out_size; (void)ws_size;
  const float* x      = (const float*)d_in[0];
  const float* w_qkv  = (const float*)d_in[1];
  const float* temp   = (const float*)d_in[2];
  const float* w_proj = (const float*)d_in[3];
  const float* b_proj = (const float*)d_in[4];
  float* out = (float*)d_out;

  char* ws = (char*)d_ws;
  _Float16* x16   = (_Float16*)(ws);
  _Float16* qkbuf = (_Float16*)(ws + 77070336L);
  _Float16* vbuf  = (_Float16*)(ws + 231211008L);
  _Float16* w16   = (_Float16*)(ws + 308281344L);
  _Float16* wp16  = (_Float16*)(ws + 311820288L);
  _Float16* out2  = x16;  // safe: x16 fully consumed before attention writes out2

  k_cvt16<<<18816, 256, 0, stream>>>(x, x16, 4816896L);
  k_cvt16<<<864,   256, 0, stream>>>(w_qkv, w16, 221184L);
  k_cvt16<<<288,   256, 0, stream>>>(w_proj, wp16, 73728L);
  // qk[c][t] = w_qkv[c,:] . x[t,:]  (c in [0,1536)) -> [1536][50176]
  k_gemm8p<0, false><<<1176, 512, 0, stream>>>(w16, x16, qkbuf, nullptr,
                                               1536, 50176, 768);
  // v[t][c] = x[t,:] . w_qkv[1536+c,:] -> [50176][768]
  k_gemm8p<1, false><<<588, 512, 0, stream>>>(x16, w16 + 1536L * 768, vbuf, nullptr,
                                              50176, 768, 768);
  k_xca_attn<<<256, 256, 0, stream>>>(qkbuf, vbuf, temp, out2);
  // out[t][c] = out2[t,:] . w_proj[c,:] + b_proj[c]  (fp32 + bias)
  k_gemm8p<2, true ><<<588, 512, 0, stream>>>(out2, wp16, out, b_proj,
                                              50176, 768, 768);
}

// Round 4
// 447.032 us; speedup vs baseline: 1.1750x; 1.0724x over previous
//
#include <hip/hip_runtime.h>
#include <hip/hip_bf16.h>
#include <stdint.h>

using f32x4   = __attribute__((ext_vector_type(4))) float;
using half8   = __attribute__((ext_vector_type(8))) _Float16;
using float4v = __attribute__((ext_vector_type(4))) float;

typedef const __attribute__((address_space(1))) void gas_void;
typedef __attribute__((address_space(3))) void las_void;

__device__ __forceinline__ void gload_lds16(const void* gptr, void* lptr) {
  __builtin_amdgcn_global_load_lds((gas_void*)(uintptr_t)gptr,
                                   (las_void*)(uintptr_t)lptr, 16, 0, 0);
}

#define MFMA_F16(a, b, c) __builtin_amdgcn_mfma_f32_16x16x32_f16((a), (b), (c), 0, 0, 0)

// ---------- fused fp32->fp16 convert for x, w_qkv, w_proj (grid-stride) ----------
__global__ void k_cvt3(const float* __restrict__ x, const float* __restrict__ wqkv,
                       const float* __restrict__ wproj,
                       _Float16* __restrict__ x16, _Float16* __restrict__ w16,
                       _Float16* __restrict__ wp16) {
  const long N0 = 4816896L, N1 = 221184L, N2 = 73728L;  // 8-elem units
  const long total = N0 + N1 + N2;
  for (long i = (long)blockIdx.x * blockDim.x + threadIdx.x; i < total;
       i += (long)gridDim.x * blockDim.x) {
    const float* src; _Float16* dst; long off;
    if (i < N0)            { src = x;     dst = x16;  off = i; }
    else if (i < N0 + N1)  { src = wqkv;  dst = w16;  off = i - N0; }
    else                   { src = wproj; dst = wp16; off = i - N0 - N1; }
    const float4v* p = (const float4v*)(src + off * 8);
    float4v a = p[0], b = p[1];
    half8 o;
    o[0] = (_Float16)a[0]; o[1] = (_Float16)a[1]; o[2] = (_Float16)a[2]; o[3] = (_Float16)a[3];
    o[4] = (_Float16)b[0]; o[5] = (_Float16)b[1]; o[6] = (_Float16)b[2]; o[7] = (_Float16)b[3];
    *(half8*)(dst + off * 8) = o;
  }
}

// ==================== 256x256 8-phase bt-GEMM, dual-descriptor ====================
// C[m][n] = sum_k A[m][k]*B[n][k]; A:[M][K], B:[N][K] row-major fp16.
// Two GEMM descriptors in one dispatch (tail-fill): swizzled wg < nwg0 -> side 0.
// 512 thr = 8 waves (2M x 4N), per-wave 128x64 out, acc[8][4]. K-tile=64 (2 K-halves),
// 2 LDS bufs, iter = 2 K-tiles = 8 phases. Counted vmcnt(4) at phases 4/8 only.
// Register-dbuf: each phase prefetches NEXT phase's fragments right after the
// pre-MFMA barrier (producers forced by the preceding vmcnt(4) + synced at that
// barrier), so MFMA never waits on same-phase ds_reads.
// Swizzle: 16B-granule ^= (row>>1)&3; linear LDS dest + pre-swizzled global src.
// Requires M,N%256==0, K%128==0.
template<bool OUT_F32>
__global__ __launch_bounds__(512, 2)
void k_gemm8p(const _Float16* __restrict__ A0, const _Float16* __restrict__ B0,
              void* __restrict__ C0, long M0, long N0d,
              const _Float16* __restrict__ A1, const _Float16* __restrict__ B1,
              void* __restrict__ C1, long M1, long N1d,
              int nwg0, const float* __restrict__ bias, long K)
{
  __shared__ _Float16 lds[65536];  // 128 KiB
  const int tid  = threadIdx.x;
  const int wv   = tid >> 6, lane = tid & 63;
  const int g    = lane >> 4, cidx = lane & 15;
  const int wr   = wv >> 2, wc = wv & 3;

  // bijective XCD swizzle (m204)
  const int nwg = (int)gridDim.x;
  const int q = nwg >> 3, r = nwg & 7;
  const int xcd = (int)blockIdx.x & 7, bidx = (int)blockIdx.x >> 3;
  int wg = (xcd < r ? xcd * (q + 1) : r * (q + 1) + (xcd - r) * q) + bidx;

  const _Float16* Aptr; const _Float16* Bptr; void* Cp; long M, N;
  if (wg < nwg0) { Aptr = A0; Bptr = B0; Cp = C0; M = M0; N = N0d; }
  else { wg -= nwg0; Aptr = A1; Bptr = B1; Cp = C1; M = M1; N = N1d; }

  const int mtiles = (int)(M >> 8), ntiles = (int)(N >> 8);
  long mt, nt;
  if (mtiles <= ntiles) { mt = wg % mtiles; nt = wg / mtiles; }
  else                  { nt = wg % ntiles; mt = wg / ntiles; }
  const long m0 = mt * 256, n0 = nt * 256;

  const int NT = (int)(K >> 6);  // K-tiles of 64
  const int NI = NT >> 1;

  const _Float16* Ab = Aptr + m0 * K;
  const _Float16* Bb = Bptr + n0 * K;

  // staging: chunk = 16 rows x 64B; lane -> row lane>>2, dest granule lane&3
  // (HW-linear), source granule pre-swizzled (l&3)^((l>>3)&3).
  const int srow = lane >> 2;
  const int sgr  = (lane & 3) ^ ((lane >> 3) & 3);

  auto stage = [&](int op, int buf, int kh, int t) {
    const _Float16* src = op ? Bb : Ab;
    const long koff = (long)t * 64 + kh * 32 + sgr * 8;
#pragma unroll
    for (int l = 0; l < 2; ++l) {
      const int chunk = l * 8 + wv;
      gload_lds16(src + (long)(chunk * 16 + srow) * K + koff,
                  &lds[buf * 32768 + op * 16384 + kh * 8192 + chunk * 512]);
    }
  };

  // fragment-read swizzled granule: g ^ ((row>>1)&3) == g ^ ((cidx>>1)&3)
  const int gr  = (g ^ ((cidx >> 1) & 3)) * 8;
  const int raA = (wr * 128 + cidx) * 32 + gr;
  const int raB = 16384 + (wc * 64 + cidx) * 32 + gr;

  f32x4 acc[8][4] = {};

  // ---- prologue: stage t0(kh0,kh1), t1(kh0); force t0 landed ----
  stage(0, 0, 0, 0); stage(1, 0, 0, 0);
  stage(0, 0, 1, 0); stage(1, 0, 1, 0);
  stage(0, 1, 0, 1); stage(1, 1, 0, 1);
  asm volatile("s_waitcnt vmcnt(4)" ::: "memory");
  __builtin_amdgcn_sched_barrier(0);
  __builtin_amdgcn_s_barrier();

  half8 afA[4], afB[4], bfA[4], bfB[4];
#pragma unroll
  for (int mm = 0; mm < 4; ++mm) afA[mm] = *(const half8*)&lds[raA + mm * 512];
#pragma unroll
  for (int nn = 0; nn < 4; ++nn) bfA[nn] = *(const half8*)&lds[raB + nn * 512];

  // Phase p: stage | vmcnt? | barrier | prefetch frags for p+1 | MFMA(cur) | barrier
#define XPH(CURA, CURB, MLO, NA, NBUF, NKS, NMLO, LOADB, NB, STAGE, BDRY)      \
  {                                                                            \
    STAGE;                                                                     \
    if (BDRY) {                                                                \
      asm volatile("s_waitcnt vmcnt(4)" ::: "memory");                         \
      __builtin_amdgcn_sched_barrier(0);                                       \
    }                                                                          \
    __builtin_amdgcn_s_barrier();                                              \
    _Pragma("unroll")                                                          \
    for (int mm = 0; mm < 4; ++mm)                                             \
      NA[mm] = *(const half8*)&lds[(NBUF)*32768 + (NKS)*8192 + raA + ((NMLO)+mm)*512]; \
    if (LOADB) {                                                               \
      _Pragma("unroll")                                                        \
      for (int nn = 0; nn < 4; ++nn)                                           \
        NB[nn] = *(const half8*)&lds[(NBUF)*32768 + (NKS)*8192 + raB + nn*512]; \
    }                                                                          \
    __builtin_amdgcn_sched_barrier(0);                                         \
    __builtin_amdgcn_s_setprio(1);                                             \
    _Pragma("unroll")                                                          \
    for (int mm = 0; mm < 4; ++mm)                                             \
      _Pragma("unroll")                                                        \
      for (int nn = 0; nn < 4; ++nn)                                           \
        acc[(MLO)+mm][nn] = MFMA_F16(CURA[mm], CURB[nn], acc[(MLO)+mm][nn]);   \
    __builtin_amdgcn_s_setprio(0);                                             \
    __builtin_amdgcn_s_barrier();                                              \
  }

  for (int it = 0; it < NI; ++it) {
    const int t1c = 2 * it + 1;
    int tn2 = 2 * it + 2; if (tn2 >= NT) tn2 -= NT;
    int tn3 = 2 * it + 3; if (tn3 >= NT) tn3 -= NT;
    XPH(afA, bfA, 0, afB, 0, 0, 4, 0, bfB, stage(0, 1, 1, t1c), false)
    XPH(afB, bfA, 4, afA, 0, 1, 0, 1, bfB, stage(1, 1, 1, t1c), false)
    XPH(afA, bfB, 0, afB, 0, 1, 4, 0, bfA, stage(0, 0, 0, tn2), false)
    XPH(afB, bfB, 4, afA, 1, 0, 0, 1, bfA, stage(1, 0, 0, tn2), true )
    XPH(afA, bfA, 0, afB, 1, 0, 4, 0, bfB, stage(0, 0, 1, tn2), false)
    XPH(afB, bfA, 4, afA, 1, 1, 0, 1, bfB, stage(1, 0, 1, tn2), false)
    XPH(afA, bfB, 0, afB, 1, 1, 4, 0, bfA, stage(0, 1, 0, tn3), false)
    XPH(afB, bfB, 4, afA, 0, 0, 0, 1, bfA, stage(1, 1, 0, tn3), true )
  }
#undef XPH

  // ---------------- epilogue ----------------
  float bv[4] = {0.f, 0.f, 0.f, 0.f};
  if (bias) {
#pragma unroll
    for (int n = 0; n < 4; ++n) bv[n] = bias[n0 + wc * 64 + n * 16 + cidx];
  }
  if constexpr (OUT_F32) {
    float* C = (float*)Cp;
#pragma unroll
    for (int m = 0; m < 8; ++m)
#pragma unroll
      for (int rr = 0; rr < 4; ++rr) {
        const long row = m0 + wr * 128 + m * 16 + g * 4 + rr;
#pragma unroll
        for (int n = 0; n < 4; ++n)
          C[row * N + (n0 + wc * 64 + n * 16 + cidx)] = acc[m][n][rr] + bv[n];
      }
  } else {
    _Float16* C = (_Float16*)Cp;
#pragma unroll
    for (int m = 0; m < 8; ++m)
#pragma unroll
      for (int rr = 0; rr < 4; ++rr) {
        const long row = m0 + wr * 128 + m * 16 + g * 4 + rr;
#pragma unroll
        for (int n = 0; n < 4; ++n)
          C[row * N + (n0 + wc * 64 + n * 16 + cidx)] = (_Float16)acc[m][n][rr];
      }
  }
}

// -------------------- XCA attention core: one block per (b,h) --------------------
__global__ __launch_bounds__(256)
void k_xca_attn(const _Float16* __restrict__ qk,
                const _Float16* __restrict__ vmat,
                const float* __restrict__ temperature,
                _Float16* __restrict__ out2)
{
  const int b = blockIdx.x >> 4;
  const int h = blockIdx.x & 15;
  const int tid = threadIdx.x;
  const int w = tid >> 6, lane = tid & 63;
  const int g = lane >> 4, c = lane & 15;
  const long T = 50176;
  const long tb = (long)b * 3136;

  __shared__ float red[4][48 * 48];
  __shared__ float redss[4][2][48];
  __shared__ float inv[2][48];
  __shared__ _Float16 Pb[48 * 48];

  f32x4 sqk[3][3] = {};
  f32x4 sqq[3] = {};
  f32x4 skk[3] = {};

  const _Float16* qbase = qk + (long)(h * 48) * T + tb;
  const _Float16* kbase = qk + (long)(768 + h * 48) * T + tb;

  for (int chunk = w; chunk < 49; chunk += 4) {
    const int t0 = chunk * 64;
    half8 qf[3][2], kf[3][2];
#pragma unroll
    for (int m = 0; m < 3; ++m)
#pragma unroll
      for (int ks = 0; ks < 2; ++ks) {
        const long off = (long)(m * 16 + c) * T + t0 + ks * 32 + g * 8;
        qf[m][ks] = *(const half8*)(qbase + off);
        kf[m][ks] = *(const half8*)(kbase + off);
      }
#pragma unroll
    for (int ks = 0; ks < 2; ++ks)
#pragma unroll
      for (int m = 0; m < 3; ++m) {
        sqq[m] = MFMA_F16(qf[m][ks], qf[m][ks], sqq[m]);
        skk[m] = MFMA_F16(kf[m][ks], kf[m][ks], skk[m]);
#pragma unroll
        for (int n = 0; n < 3; ++n)
          sqk[m][n] = MFMA_F16(qf[m][ks], kf[n][ks], sqk[m][n]);
      }
  }

#pragma unroll
  for (int m = 0; m < 3; ++m) {
#pragma unroll
    for (int n = 0; n < 3; ++n)
#pragma unroll
      for (int r = 0; r < 4; ++r)
        red[w][(m * 16 + g * 4 + r) * 48 + n * 16 + c] = sqk[m][n][r];
#pragma unroll
    for (int r = 0; r < 4; ++r)
      if (c == g * 4 + r) {
        redss[w][0][m * 16 + c] = sqq[m][r];
        redss[w][1][m * 16 + c] = skk[m][r];
      }
  }
  __syncthreads();

  if (tid < 96) {
    const int is_k = tid / 48, d = tid % 48;
    const float s = redss[0][is_k][d] + redss[1][is_k][d] + redss[2][is_k][d] + redss[3][is_k][d];
    inv[is_k][d] = 1.0f / fmaxf(sqrtf(s), 1e-12f);
  }
  __syncthreads();

  if (tid < 48) {
    const int d = tid;
    const float iq = inv[0][d] * temperature[h];
    float rowv[48];
    float mx = -3.0e38f;
#pragma unroll
    for (int e = 0; e < 48; ++e) {
      const int idx = d * 48 + e;
      float t = (red[0][idx] + red[1][idx] + red[2][idx] + red[3][idx]) * iq * inv[1][e];
      rowv[e] = t;
      mx = fmaxf(mx, t);
    }
    float sum = 0.f;
#pragma unroll
    for (int e = 0; e < 48; ++e) {
      const float p = __expf(rowv[e] - mx);
      rowv[e] = p;
      sum += p;
    }
    const float is = 1.0f / sum;
#pragma unroll
    for (int e = 0; e < 48; ++e)
      Pb[d * 48 + e] = (_Float16)(rowv[e] * is);
  }
  __syncthreads();

  half8 hz;
#pragma unroll
  for (int j = 0; j < 8; ++j) hz[j] = (_Float16)0.f;

  half8 pf[3][2];
#pragma unroll
  for (int n = 0; n < 3; ++n)
#pragma unroll
    for (int ks = 0; ks < 2; ++ks) {
      const int e = ks * 32 + g * 8;
      pf[n][ks] = (e < 48) ? *(const half8*)&Pb[(n * 16 + c) * 48 + e] : hz;
    }

  const _Float16* vbase = vmat + tb * 768 + h * 48;
  _Float16* obase = out2 + tb * 768 + h * 48;

  for (int chunk = w; chunk < 49; chunk += 4) {
    const int t0 = chunk * 64;
    half8 vf[4][2];
#pragma unroll
    for (int m = 0; m < 4; ++m)
#pragma unroll
      for (int ks = 0; ks < 2; ++ks) {
        const int e = ks * 32 + g * 8;
        vf[m][ks] = (e < 48) ? *(const half8*)(vbase + (long)(t0 + m * 16 + c) * 768 + e) : hz;
      }
    f32x4 acc[4][3];
#pragma unroll
    for (int m = 0; m < 4; ++m)
#pragma unroll
      for (int n = 0; n < 3; ++n) {
        f32x4 z = {0.f, 0.f, 0.f, 0.f};
        acc[m][n] = z;
      }
#pragma unroll
    for (int ks = 0; ks < 2; ++ks)
#pragma unroll
      for (int m = 0; m < 4; ++m)
#pragma unroll
        for (int n = 0; n < 3; ++n)
          acc[m][n] = MFMA_F16(vf[m][ks], pf[n][ks], acc[m][n]);
#pragma unroll
    for (int m = 0; m < 4; ++m)
#pragma unroll
      for (int r = 0; r < 4; ++r) {
        const long t = t0 + m * 16 + g * 4 + r;
#pragma unroll
        for (int n = 0; n < 3; ++n)
          obase[t * 768 + n * 16 + c] = (_Float16)acc[m][n][r];
      }
  }
}

// -------------------- launch --------------------
extern "C" void kernel_launch(void* const* d_in, const int* in_sizes, int n_in,
                              void* d_out, int out_size, void* d_ws, size_t ws_size,
                              hipStream_t stream)
{
  (void)in_sizes; (void)n_in; (void)out_size; (void)ws_size;
  const float* x      = (const float*)d_in[0];
  const float* w_qkv  = (const float*)d_in[1];
  const float* temp   = (const float*)d_in[2];
  const float* w_proj = (const float*)d_in[3];
  const float* b_proj = (const float*)d_in[4];
  float* out = (float*)d_out;

  char* ws = (char*)d_ws;
  _Float16* x16   = (_Float16*)(ws);
  _Float16* qkbuf = (_Float16*)(ws + 77070336L);
  _Float16* vbuf  = (_Float16*)(ws + 231211008L);
  _Float16* w16   = (_Float16*)(ws + 308281344L);
  _Float16* wp16  = (_Float16*)(ws + 311820288L);
  _Float16* out2  = x16;  // safe: x16 fully consumed before attention writes out2

  k_cvt3<<<2048, 256, 0, stream>>>(x, w_qkv, w_proj, x16, w16, wp16);
  // merged: side0 = QK gemm (qk[c][t], 1176 tiles), side1 = V gemm (v[t][c], 588 tiles)
  k_gemm8p<false><<<1764, 512, 0, stream>>>(w16, x16, qkbuf, 1536, 50176,
                                            x16, w16 + 1536L * 768, vbuf, 50176, 768,
                                            1176, nullptr, 768);
  k_xca_attn<<<256, 256, 0, stream>>>(qkbuf, vbuf, temp, out2);
  // proj: out[t][c] = out2[t,:] . w_proj[c,:] + b_proj[c]  (fp32 + bias)
  k_gemm8p<true ><<<588, 512, 0, stream>>>(out2, wp16, out, 50176, 768,
                                           nullptr, nullptr, nullptr, 0, 0,
                                           588, b_proj, 768);
}

// Round 5
// 365.928 us; speedup vs baseline: 1.4354x; 1.2216x over previous
//
#include <hip/hip_runtime.h>
#include <hip/hip_bf16.h>
#include <stdint.h>

using f32x4   = __attribute__((ext_vector_type(4))) float;
using half8   = __attribute__((ext_vector_type(8))) _Float16;
using float4v = __attribute__((ext_vector_type(4))) float;

typedef const __attribute__((address_space(1))) void gas_void;
typedef __attribute__((address_space(3))) void las_void;

__device__ __forceinline__ void gload_lds16(const void* gptr, void* lptr) {
  __builtin_amdgcn_global_load_lds((gas_void*)(uintptr_t)gptr,
                                   (las_void*)(uintptr_t)lptr, 16, 0, 0);
}

#define MFMA_F16(a, b, c) __builtin_amdgcn_mfma_f32_16x16x32_f16((a), (b), (c), 0, 0, 0)

// ---------- fused fp32->fp16 convert: x, w_qkv, w_proj, wvT (grid-stride) ----------
// wvT[h][f][e] = w_qkv[1536 + h*48 + e][f], e-padded to 64 with zeros.
__global__ void k_cvt4(const float* __restrict__ x, const float* __restrict__ wqkv,
                       const float* __restrict__ wproj,
                       _Float16* __restrict__ x16, _Float16* __restrict__ w16,
                       _Float16* __restrict__ wp16, _Float16* __restrict__ wvT) {
  const long N0 = 4816896L, N1 = 221184L, N2 = 73728L, N3 = 98304L; // 8-elem units
  const long total = N0 + N1 + N2 + N3;
  for (long i = (long)blockIdx.x * blockDim.x + threadIdx.x; i < total;
       i += (long)gridDim.x * blockDim.x) {
    if (i < N0 + N1 + N2) {
      const float* src; _Float16* dst; long off;
      if (i < N0)            { src = x;     dst = x16;  off = i; }
      else if (i < N0 + N1)  { src = wqkv;  dst = w16;  off = i - N0; }
      else                   { src = wproj; dst = wp16; off = i - N0 - N1; }
      const float4v* p = (const float4v*)(src + off * 8);
      float4v a = p[0], b = p[1];
      half8 o;
      o[0] = (_Float16)a[0]; o[1] = (_Float16)a[1]; o[2] = (_Float16)a[2]; o[3] = (_Float16)a[3];
      o[4] = (_Float16)b[0]; o[5] = (_Float16)b[1]; o[6] = (_Float16)b[2]; o[7] = (_Float16)b[3];
      *(half8*)(dst + off * 8) = o;
    } else {
      const long u = i - (N0 + N1 + N2);
      const int h = (int)(u / 6144);
      const int r = (int)(u % 6144);
      const int f = r >> 3, e0 = (r & 7) * 8;
      half8 o;
      if (e0 >= 48) {
#pragma unroll
        for (int j = 0; j < 8; ++j) o[j] = (_Float16)0.f;
      } else {
#pragma unroll
        for (int j = 0; j < 8; ++j)
          o[j] = (_Float16)wqkv[(long)(1536 + h * 48 + e0 + j) * 768 + f];
      }
      *(half8*)(wvT + ((long)(h * 768 + f) * 64 + e0)) = o;
    }
  }
}

// ==================== 256x256 8-phase bt-GEMM, batched + M-tail mask ====================
// C[m][n] = sum_k A[m][k]*B[n][k]. Per batch: A [Mt*256 rows, valid < Areal][K],
// B [N][K], C [Areal rows][N]. Tail-tile A reads past Areal hit adjacent ws memory
// (mapped); garbage rows only affect their own (masked) C rows. Requires K%128==0.
template<bool OUT_F32>
__global__ __launch_bounds__(512, 2)
void k_gemm8p(const _Float16* __restrict__ A, const _Float16* __restrict__ B,
              void* __restrict__ Cv, const float* __restrict__ bias,
              int Mt, int Nt, long Areal, long Astr, long Bstr, long Cstr,
              long N, long K)
{
  __shared__ _Float16 lds[65536];  // 128 KiB
  const int tid  = threadIdx.x;
  const int wv   = tid >> 6, lane = tid & 63;
  const int g    = lane >> 4, cidx = lane & 15;
  const int wr   = wv >> 2, wc = wv & 3;

  // bijective XCD swizzle (m204)
  const int nwg = (int)gridDim.x;
  const int q = nwg >> 3, r = nwg & 7;
  const int xcd = (int)blockIdx.x & 7, bidx = (int)blockIdx.x >> 3;
  int wg = (xcd < r ? xcd * (q + 1) : r * (q + 1) + (xcd - r) * q) + bidx;

  const int tpb = Mt * Nt;
  const int b   = wg / tpb;
  const int rem = wg - b * tpb;
  const long mt = rem % Mt, nt = rem / Mt;   // mt fast: consecutive blocks share B panel
  const long m0 = mt * 256, n0 = nt * 256;

  const int NT = (int)(K >> 6);
  const int NI = NT >> 1;

  const _Float16* Ab = A + b * Astr + m0 * K;
  const _Float16* Bb = B + b * Bstr + n0 * K;

  const int srow = lane >> 2;
  const int sgr  = (lane & 3) ^ ((lane >> 3) & 3);

  auto stage = [&](int op, int buf, int kh, int t) {
    const _Float16* src = op ? Bb : Ab;
    const long koff = (long)t * 64 + kh * 32 + sgr * 8;
#pragma unroll
    for (int l = 0; l < 2; ++l) {
      const int chunk = l * 8 + wv;
      gload_lds16(src + (long)(chunk * 16 + srow) * K + koff,
                  &lds[buf * 32768 + op * 16384 + kh * 8192 + chunk * 512]);
    }
  };

  const int gr  = (g ^ ((cidx >> 1) & 3)) * 8;
  const int raA = (wr * 128 + cidx) * 32 + gr;
  const int raB = 16384 + (wc * 64 + cidx) * 32 + gr;

  f32x4 acc[8][4] = {};

  stage(0, 0, 0, 0); stage(1, 0, 0, 0);
  stage(0, 0, 1, 0); stage(1, 0, 1, 0);
  stage(0, 1, 0, 1); stage(1, 1, 0, 1);
  asm volatile("s_waitcnt vmcnt(4)" ::: "memory");
  __builtin_amdgcn_sched_barrier(0);
  __builtin_amdgcn_s_barrier();

  half8 afA[4], afB[4], bfA[4], bfB[4];
#pragma unroll
  for (int mm = 0; mm < 4; ++mm) afA[mm] = *(const half8*)&lds[raA + mm * 512];
#pragma unroll
  for (int nn = 0; nn < 4; ++nn) bfA[nn] = *(const half8*)&lds[raB + nn * 512];

#define XPH(CURA, CURB, MLO, NA, NBUF, NKS, NMLO, LOADB, NB, STAGE, BDRY)      \
  {                                                                            \
    STAGE;                                                                     \
    if (BDRY) {                                                                \
      asm volatile("s_waitcnt vmcnt(4)" ::: "memory");                         \
      __builtin_amdgcn_sched_barrier(0);                                       \
    }                                                                          \
    __builtin_amdgcn_s_barrier();                                              \
    _Pragma("unroll")                                                          \
    for (int mm = 0; mm < 4; ++mm)                                             \
      NA[mm] = *(const half8*)&lds[(NBUF)*32768 + (NKS)*8192 + raA + ((NMLO)+mm)*512]; \
    if (LOADB) {                                                               \
      _Pragma("unroll")                                                        \
      for (int nn = 0; nn < 4; ++nn)                                           \
        NB[nn] = *(const half8*)&lds[(NBUF)*32768 + (NKS)*8192 + raB + nn*512]; \
    }                                                                          \
    __builtin_amdgcn_sched_barrier(0);                                         \
    __builtin_amdgcn_s_setprio(1);                                             \
    _Pragma("unroll")                                                          \
    for (int mm = 0; mm < 4; ++mm)                                             \
      _Pragma("unroll")                                                        \
      for (int nn = 0; nn < 4; ++nn)                                           \
        acc[(MLO)+mm][nn] = MFMA_F16(CURA[mm], CURB[nn], acc[(MLO)+mm][nn]);   \
    __builtin_amdgcn_s_setprio(0);                                             \
    __builtin_amdgcn_s_barrier();                                              \
  }

  for (int it = 0; it < NI; ++it) {
    const int t1c = 2 * it + 1;
    int tn2 = 2 * it + 2; if (tn2 >= NT) tn2 -= NT;
    int tn3 = 2 * it + 3; if (tn3 >= NT) tn3 -= NT;
    XPH(afA, bfA, 0, afB, 0, 0, 4, 0, bfB, stage(0, 1, 1, t1c), false)
    XPH(afB, bfA, 4, afA, 0, 1, 0, 1, bfB, stage(1, 1, 1, t1c), false)
    XPH(afA, bfB, 0, afB, 0, 1, 4, 0, bfA, stage(0, 0, 0, tn2), false)
    XPH(afB, bfB, 4, afA, 1, 0, 0, 1, bfA, stage(1, 0, 0, tn2), true )
    XPH(afA, bfA, 0, afB, 1, 0, 4, 0, bfB, stage(0, 0, 1, tn2), false)
    XPH(afB, bfA, 4, afA, 1, 1, 0, 1, bfB, stage(1, 0, 1, tn2), false)
    XPH(afA, bfB, 0, afB, 1, 1, 4, 0, bfA, stage(0, 1, 0, tn3), false)
    XPH(afB, bfB, 4, afA, 0, 0, 0, 1, bfA, stage(1, 1, 0, tn3), true )
  }
#undef XPH

  float bv[4] = {0.f, 0.f, 0.f, 0.f};
  if (bias) {
#pragma unroll
    for (int n = 0; n < 4; ++n) bv[n] = bias[n0 + wc * 64 + n * 16 + cidx];
  }
  if constexpr (OUT_F32) {
    float* C = (float*)Cv + b * Cstr;
#pragma unroll
    for (int m = 0; m < 8; ++m)
#pragma unroll
      for (int rr = 0; rr < 4; ++rr) {
        const long row = m0 + wr * 128 + m * 16 + g * 4 + rr;
        if (row < Areal) {
#pragma unroll
          for (int n = 0; n < 4; ++n)
            C[row * N + (n0 + wc * 64 + n * 16 + cidx)] = acc[m][n][rr] + bv[n];
        }
      }
  } else {
    _Float16* C = (_Float16*)Cv + b * Cstr;
#pragma unroll
    for (int m = 0; m < 8; ++m)
#pragma unroll
      for (int rr = 0; rr < 4; ++rr) {
        const long row = m0 + wr * 128 + m * 16 + g * 4 + rr;
        if (row < Areal) {
#pragma unroll
          for (int n = 0; n < 4; ++n)
            C[row * N + (n0 + wc * 64 + n * 16 + cidx)] = (_Float16)acc[m][n][rr];
        }
      }
  }
}

// ==================== 128x128 bt-GEMM (Wfin = Wp . WeffT^T, per batch) ====================
// C_b[o][f] = sum_c Wp[o][c] * WeffT_b[f][c]. M=N=K=768. Grid 16*36.
__global__ __launch_bounds__(256)
void k_wfin(const _Float16* __restrict__ Ag, const _Float16* __restrict__ Bg,
            _Float16* __restrict__ Cg)
{
  __shared__ _Float16 lds[2][2][128 * 32];
  const int tid  = threadIdx.x;
  const int wv   = tid >> 6, lane = tid & 63;
  const int g    = lane >> 4, cidx = lane & 15;
  const int wr   = wv >> 1, wc = wv & 1;

  const int nwg = (int)gridDim.x;
  const int q = nwg >> 3, r = nwg & 7;
  const int xcd = (int)blockIdx.x & 7, bidx = (int)blockIdx.x >> 3;
  const int wg  = (xcd < r ? xcd * (q + 1) : r * (q + 1) + (xcd - r) * q) + bidx;

  const int b = wg / 36, rem = wg % 36;
  const int mt = rem % 6, nt = rem / 6;
  const _Float16* Ab = Ag + (long)mt * 128 * 768;
  const _Float16* Bb = Bg + (long)b * 589824 + (long)nt * 128 * 768;
  _Float16* C = Cg + (long)b * 589824;

  const int srow = lane >> 2;
  const int sgr  = (lane & 3) ^ ((lane >> 3) & 3);

  auto stage = [&](int buf, int kt) {
#pragma unroll
    for (int i = 0; i < 2; ++i) {
      const int chunk = wv * 2 + i;
      const long go = (long)(chunk * 16 + srow) * 768 + (long)kt * 32 + sgr * 8;
      gload_lds16(Ab + go, &lds[buf][0][chunk * 512]);
      gload_lds16(Bb + go, &lds[buf][1][chunk * 512]);
    }
  };

  const int gr = (g ^ ((cidx >> 1) & 3)) * 8;

  f32x4 acc[4][4] = {};
  stage(0, 0);
  __syncthreads();
  for (int kt = 0; kt < 24; ++kt) {
    const int cur = kt & 1;
    if (kt + 1 < 24) stage(cur ^ 1, kt + 1);
    const _Float16* la = &lds[cur][0][0];
    const _Float16* lb = &lds[cur][1][0];
    half8 af[4], bf[4];
#pragma unroll
    for (int m = 0; m < 4; ++m)
      af[m] = *(const half8*)&la[(wr * 64 + m * 16 + cidx) * 32 + gr];
#pragma unroll
    for (int n = 0; n < 4; ++n)
      bf[n] = *(const half8*)&lb[(wc * 64 + n * 16 + cidx) * 32 + gr];
#pragma unroll
    for (int m = 0; m < 4; ++m)
#pragma unroll
      for (int n = 0; n < 4; ++n)
        acc[m][n] = MFMA_F16(af[m], bf[n], acc[m][n]);
    __syncthreads();
  }
#pragma unroll
  for (int m = 0; m < 4; ++m)
#pragma unroll
    for (int rr = 0; rr < 4; ++rr) {
      const long row = mt * 128 + wr * 64 + m * 16 + g * 4 + rr;
#pragma unroll
      for (int n = 0; n < 4; ++n)
        C[row * 768 + (nt * 128 + wc * 64 + n * 16 + cidx)] = (_Float16)acc[m][n][rr];
    }
}

// ==================== heads: S + norms + softmax + WeffT, one block per (b,h) ====================
// Phase A: S = q.k^T + q/k sumsq via MFMA over tokens from qkbuf (unchanged math).
// Then WeffT_b[f][h*48+d] = sum_e Wv[e][f] P[d][e], via MFMA(A=wvT[f][e], B=P[d][e]).
__global__ __launch_bounds__(256)
void k_heads(const _Float16* __restrict__ qk,
             const _Float16* __restrict__ wvT,
             const float* __restrict__ temperature,
             _Float16* __restrict__ weffT)
{
  const int b = blockIdx.x >> 4;
  const int h = blockIdx.x & 15;
  const int tid = threadIdx.x;
  const int w = tid >> 6, lane = tid & 63;
  const int g = lane >> 4, c = lane & 15;
  const long T = 50176;
  const long tb = (long)b * 3136;

  __shared__ float red[4][48 * 48];
  __shared__ float redss[4][2][48];
  __shared__ float inv[2][48];
  __shared__ _Float16 Pb[48 * 64];   // stride 64, e-padded with zeros

  f32x4 sqk[3][3] = {};
  f32x4 sqq[3] = {};
  f32x4 skk[3] = {};

  const _Float16* qbase = qk + (long)(h * 48) * T + tb;
  const _Float16* kbase = qk + (long)(768 + h * 48) * T + tb;

  for (int chunk = w; chunk < 49; chunk += 4) {
    const int t0 = chunk * 64;
    half8 qf[3][2], kf[3][2];
#pragma unroll
    for (int m = 0; m < 3; ++m)
#pragma unroll
      for (int ks = 0; ks < 2; ++ks) {
        const long off = (long)(m * 16 + c) * T + t0 + ks * 32 + g * 8;
        qf[m][ks] = *(const half8*)(qbase + off);
        kf[m][ks] = *(const half8*)(kbase + off);
      }
#pragma unroll
    for (int ks = 0; ks < 2; ++ks)
#pragma unroll
      for (int m = 0; m < 3; ++m) {
        sqq[m] = MFMA_F16(qf[m][ks], qf[m][ks], sqq[m]);
        skk[m] = MFMA_F16(kf[m][ks], kf[m][ks], skk[m]);
#pragma unroll
        for (int n = 0; n < 3; ++n)
          sqk[m][n] = MFMA_F16(qf[m][ks], kf[n][ks], sqk[m][n]);
      }
  }

#pragma unroll
  for (int m = 0; m < 3; ++m) {
#pragma unroll
    for (int n = 0; n < 3; ++n)
#pragma unroll
      for (int r = 0; r < 4; ++r)
        red[w][(m * 16 + g * 4 + r) * 48 + n * 16 + c] = sqk[m][n][r];
#pragma unroll
    for (int r = 0; r < 4; ++r)
      if (c == g * 4 + r) {
        redss[w][0][m * 16 + c] = sqq[m][r];
        redss[w][1][m * 16 + c] = skk[m][r];
      }
  }
  __syncthreads();

  if (tid < 96) {
    const int is_k = tid / 48, d = tid % 48;
    const float s = redss[0][is_k][d] + redss[1][is_k][d] + redss[2][is_k][d] + redss[3][is_k][d];
    inv[is_k][d] = 1.0f / fmaxf(sqrtf(s), 1e-12f);
  }
  __syncthreads();

  if (tid < 48) {
    const int d = tid;
    const float iq = inv[0][d] * temperature[h];
    float rowv[48];
    float mx = -3.0e38f;
#pragma unroll
    for (int e = 0; e < 48; ++e) {
      const int idx = d * 48 + e;
      float t = (red[0][idx] + red[1][idx] + red[2][idx] + red[3][idx]) * iq * inv[1][e];
      rowv[e] = t;
      mx = fmaxf(mx, t);
    }
    float sum = 0.f;
#pragma unroll
    for (int e = 0; e < 48; ++e) {
      const float p = __expf(rowv[e] - mx);
      rowv[e] = p;
      sum += p;
    }
    const float is = 1.0f / sum;
#pragma unroll
    for (int e = 0; e < 48; ++e)
      Pb[d * 64 + e] = (_Float16)(rowv[e] * is);
#pragma unroll
    for (int e = 48; e < 64; ++e)
      Pb[d * 64 + e] = (_Float16)0.f;
  }
  __syncthreads();

  // ---- WeffT: per wave 12 f-frags x 3 d-frags, K=64 (2 steps) ----
  half8 pf[3][2];
#pragma unroll
  for (int nf = 0; nf < 3; ++nf)
#pragma unroll
    for (int ks = 0; ks < 2; ++ks)
      pf[nf][ks] = *(const half8*)&Pb[(nf * 16 + c) * 64 + ks * 32 + g * 8];

  const _Float16* wvh = wvT + (long)h * 768 * 64;
  _Float16* wout = weffT + (long)b * 589824 + h * 48;

  for (int m = 0; m < 12; ++m) {
    const int f0 = w * 192 + m * 16;
    half8 va[2];
#pragma unroll
    for (int ks = 0; ks < 2; ++ks)
      va[ks] = *(const half8*)&wvh[(long)(f0 + c) * 64 + ks * 32 + g * 8];
    f32x4 a3[3] = {};
#pragma unroll
    for (int ks = 0; ks < 2; ++ks)
#pragma unroll
      for (int nf = 0; nf < 3; ++nf)
        a3[nf] = MFMA_F16(va[ks], pf[nf][ks], a3[nf]);
#pragma unroll
    for (int nf = 0; nf < 3; ++nf)
#pragma unroll
      for (int r = 0; r < 4; ++r)
        wout[(long)(f0 + g * 4 + r) * 768 + nf * 16 + c] = (_Float16)a3[nf][r];
  }
}

// -------------------- launch --------------------
extern "C" void kernel_launch(void* const* d_in, const int* in_sizes, int n_in,
                              void* d_out, int out_size, void* d_ws, size_t ws_size,
                              hipStream_t stream)
{
  (void)in_sizes; (void)n_in; (void)out_size; (void)ws_size;
  const float* x      = (const float*)d_in[0];
  const float* w_qkv  = (const float*)d_in[1];
  const float* temp   = (const float*)d_in[2];
  const float* w_proj = (const float*)d_in[3];
  const float* b_proj = (const float*)d_in[4];
  float* out = (float*)d_out;

  // ws layout (bytes):
  //   [0)          x16   : 77,070,336   [50176][768] fp16
  //   [77070336)   qkbuf : 154,140,672  [1536][50176] fp16
  //   [231211008)  weffT : 18,874,368   [16][768 f][768 c] fp16
  //   [250085376)  wfin  : 18,874,368   [16][768 o][768 f] fp16
  //   [268959744)  w16   : 3,538,944    [2304][768] fp16
  //   [272498688)  wp16  : 1,179,648    [768][768] fp16
  //   [273678336)  wvT   : 1,572,864    [16][768][64] fp16 (e-padded)
  char* ws = (char*)d_ws;
  _Float16* x16   = (_Float16*)(ws);
  _Float16* qkbuf = (_Float16*)(ws + 77070336L);
  _Float16* weffT = (_Float16*)(ws + 231211008L);
  _Float16* wfin  = (_Float16*)(ws + 250085376L);
  _Float16* w16   = (_Float16*)(ws + 268959744L);
  _Float16* wp16  = (_Float16*)(ws + 272498688L);
  _Float16* wvT   = (_Float16*)(ws + 273678336L);

  k_cvt4<<<2048, 256, 0, stream>>>(x, w_qkv, w_proj, x16, w16, wp16, wvT);
  // qk[c][t] = w_qkv[c,:] . x[t,:]  (c in [0,1536)) -> [1536][50176]
  k_gemm8p<false><<<1176, 512, 0, stream>>>(w16, x16, qkbuf, nullptr,
                                            6, 196, 1536, 0, 0, 0, 50176, 768);
  // per (b,h): S, norms, softmax, WeffT
  k_heads<<<256, 256, 0, stream>>>(qkbuf, wvT, temp, weffT);
  // Wfin_b = Wp . Weff_b  (bt with B=WeffT)
  k_wfin<<<576, 256, 0, stream>>>(wp16, weffT, wfin);
  // final_b[t][o] = x_b[t,:] . Wfin_b[o,:] + bias[o]  (fp32 out, M-tail masked)
  k_gemm8p<true><<<624, 512, 0, stream>>>(x16, wfin, out, b_proj,
                                          13, 3, 3136, 3136L * 768, 589824, 3136L * 768,
                                          768, 768);
}

// Round 6
// 339.939 us; speedup vs baseline: 1.5452x; 1.0765x over previous
//
#include <hip/hip_runtime.h>
#include <hip/hip_bf16.h>
#include <stdint.h>

using f32x4   = __attribute__((ext_vector_type(4))) float;
using half8   = __attribute__((ext_vector_type(8))) _Float16;
using half4   = __attribute__((ext_vector_type(4))) _Float16;
using float4v = __attribute__((ext_vector_type(4))) float;

typedef const __attribute__((address_space(1))) void gas_void;
typedef __attribute__((address_space(3))) void las_void;

__device__ __forceinline__ void gload_lds16(const void* gptr, void* lptr) {
  __builtin_amdgcn_global_load_lds((gas_void*)(uintptr_t)gptr,
                                   (las_void*)(uintptr_t)lptr, 16, 0, 0);
}

#define MFMA_F16(a, b, c) __builtin_amdgcn_mfma_f32_16x16x32_f16((a), (b), (c), 0, 0, 0)

// ---------- weights fp32->fp16: w16 (2304x768), wp16, wvT (grid-stride) ----------
// wvT[h][f][e] = w_qkv[1536 + h*48 + e][f], e-padded to 64 with zeros.
__global__ void k_cvtw(const float* __restrict__ wqkv, const float* __restrict__ wproj,
                       _Float16* __restrict__ w16, _Float16* __restrict__ wp16,
                       _Float16* __restrict__ wvT) {
  const long N1 = 221184L, N2 = 73728L, N3 = 98304L;  // 8-elem units
  const long total = N1 + N2 + N3;
  for (long i = (long)blockIdx.x * blockDim.x + threadIdx.x; i < total;
       i += (long)gridDim.x * blockDim.x) {
    if (i < N1 + N2) {
      const float* src; _Float16* dst; long off;
      if (i < N1) { src = wqkv;  dst = w16;  off = i; }
      else        { src = wproj; dst = wp16; off = i - N1; }
      const float4v* p = (const float4v*)(src + off * 8);
      float4v a = p[0], b = p[1];
      half8 o;
      o[0] = (_Float16)a[0]; o[1] = (_Float16)a[1]; o[2] = (_Float16)a[2]; o[3] = (_Float16)a[3];
      o[4] = (_Float16)b[0]; o[5] = (_Float16)b[1]; o[6] = (_Float16)b[2]; o[7] = (_Float16)b[3];
      *(half8*)(dst + off * 8) = o;
    } else {
      const long u = i - N1 - N2;
      const int h = (int)(u / 6144);
      const int r = (int)(u % 6144);
      const int f = r >> 3, e0 = (r & 7) * 8;
      half8 o;
      if (e0 >= 48) {
#pragma unroll
        for (int j = 0; j < 8; ++j) o[j] = (_Float16)0.f;
      } else {
#pragma unroll
        for (int j = 0; j < 8; ++j)
          o[j] = (_Float16)wqkv[(long)(1536 + h * 48 + e0 + j) * 768 + f];
      }
      *(half8*)(wvT + ((long)(h * 768 + f) * 64 + e0)) = o;
    }
  }
}

// ---------- x fp32 -> x16 [50176][768] AND xT [16][768][3136] (tile transpose) ----------
__global__ __launch_bounds__(256)
void k_cvtx(const float* __restrict__ x, _Float16* __restrict__ x16,
            _Float16* __restrict__ xT) {
  __shared__ _Float16 lt[64 * 68];
  const int bid = blockIdx.x;
  const int b = bid / 588;            // 49 t-tiles * 12 c-tiles
  const int rem = bid % 588;
  const int tt = rem / 12, ct = rem % 12;
  const long t0g = (long)b * 3136 + tt * 64;
  const int c0 = ct * 64;
  const int tid = threadIdx.x;
#pragma unroll
  for (int ch = 0; ch < 4; ++ch) {
    const int idx = tid + ch * 256;
    const int tr = idx >> 4, cg = (idx & 15) * 4;
    float4v v = *(const float4v*)&x[(t0g + tr) * 768 + c0 + cg];
    half4 hv;
    hv[0] = (_Float16)v[0]; hv[1] = (_Float16)v[1];
    hv[2] = (_Float16)v[2]; hv[3] = (_Float16)v[3];
    *(half4*)&x16[(t0g + tr) * 768 + c0 + cg] = hv;
    *(half4*)&lt[tr * 68 + cg] = hv;
  }
  __syncthreads();
  const int c = tid >> 2, tch = tid & 3;
  half8 o0, o1;
#pragma unroll
  for (int j = 0; j < 8; ++j) o0[j] = lt[(tch * 16 + j) * 68 + c];
#pragma unroll
  for (int j = 0; j < 8; ++j) o1[j] = lt[(tch * 16 + 8 + j) * 68 + c];
  _Float16* dst = xT + (long)b * 2408448 + (long)(c0 + c) * 3136 + tt * 64 + tch * 16;
  *(half8*)dst = o0;
  *(half8*)(dst + 8) = o1;
}

// ==================== Gram: G_b = xT_b . xT_b^T, symmetric 128^2 tiles ====================
// 21 upper-tri tiles per batch (mt<=nt), mirror-write off-diagonal tiles.
__global__ __launch_bounds__(256)
void k_gram(const _Float16* __restrict__ xT, _Float16* __restrict__ G) {
  __shared__ _Float16 lds[2][2][128 * 32];
  const int tid = threadIdx.x;
  const int wv = tid >> 6, lane = tid & 63;
  const int g = lane >> 4, cidx = lane & 15;
  const int wr = wv >> 1, wc = wv & 1;

  const int nwg = (int)gridDim.x;
  const int q = nwg >> 3, r = nwg & 7;
  const int xcd = (int)blockIdx.x & 7, bidx = (int)blockIdx.x >> 3;
  int wg = (xcd < r ? xcd * (q + 1) : r * (q + 1) + (xcd - r) * q) + bidx;
  const int b = wg / 21;
  int p = wg % 21;
  int mt = 0;
  while (p >= 6 - mt) { p -= 6 - mt; ++mt; }
  const int nt = mt + p;

  const _Float16* Ab = xT + (long)b * 2408448 + (long)mt * 128 * 3136;
  const _Float16* Bb = xT + (long)b * 2408448 + (long)nt * 128 * 3136;

  const int srow = lane >> 2;
  const int sgr  = (lane & 3) ^ ((lane >> 3) & 3);

  auto stage = [&](int buf, int kt) {
#pragma unroll
    for (int l = 0; l < 2; ++l) {
      const int rbase = wv * 32 + l * 16;
      const long koff = (long)kt * 32 + sgr * 8;
      gload_lds16(Ab + (long)(rbase + srow) * 3136 + koff, &lds[buf][0][rbase * 32]);
      gload_lds16(Bb + (long)(rbase + srow) * 3136 + koff, &lds[buf][1][rbase * 32]);
    }
  };
  const int gr = (g ^ ((cidx >> 1) & 3)) * 8;

  f32x4 acc[4][4] = {};
  stage(0, 0);
  __syncthreads();
  for (int kt = 0; kt < 98; ++kt) {
    const int cur = kt & 1;
    if (kt + 1 < 98) stage(cur ^ 1, kt + 1);
    half8 af[4], bf[4];
#pragma unroll
    for (int m = 0; m < 4; ++m)
      af[m] = *(const half8*)&lds[cur][0][(wr * 64 + m * 16 + cidx) * 32 + gr];
#pragma unroll
    for (int n = 0; n < 4; ++n)
      bf[n] = *(const half8*)&lds[cur][1][(wc * 64 + n * 16 + cidx) * 32 + gr];
#pragma unroll
    for (int m = 0; m < 4; ++m)
#pragma unroll
      for (int n = 0; n < 4; ++n)
        acc[m][n] = MFMA_F16(af[m], bf[n], acc[m][n]);
    __syncthreads();
  }
  _Float16* Gb = G + (long)b * 589824;
  const long m0 = (long)mt * 128, n0 = (long)nt * 128;
#pragma unroll
  for (int m = 0; m < 4; ++m)
#pragma unroll
    for (int rr = 0; rr < 4; ++rr) {
      const long row = m0 + wr * 64 + m * 16 + g * 4 + rr;
#pragma unroll
      for (int n = 0; n < 4; ++n)
        Gb[row * 768 + n0 + wc * 64 + n * 16 + cidx] = (_Float16)acc[m][n][rr];
    }
  if (mt != nt) {
#pragma unroll
    for (int m = 0; m < 4; ++m)
#pragma unroll
      for (int n = 0; n < 4; ++n) {
        half4 hv;
#pragma unroll
        for (int rr = 0; rr < 4; ++rr) hv[rr] = (_Float16)acc[m][n][rr];
        const long col  = n0 + wc * 64 + n * 16 + cidx;
        const long row0 = m0 + wr * 64 + m * 16 + g * 4;
        *(half4*)&Gb[col * 768 + row0] = hv;
      }
  }
}

// ==================== generic batched 128^2 bt-GEMM (QG / wfin / final) ====================
// C[m][n] = sum_k A[m][k]*B[n][k]; per batch offsets Astr/Bstr/Cstr (element units).
// mt fast-varying (consecutive blocks share the B panel). Rows >= Areal masked on store.
template<bool OUT_F32>
__global__ __launch_bounds__(256)
void k_g128(const _Float16* __restrict__ A, const _Float16* __restrict__ B,
            void* __restrict__ Cv, const float* __restrict__ bias,
            int Mt, int Nt, long Areal, long Astr, long Bstr, long Cstr,
            long N, long K)
{
  __shared__ _Float16 lds[2][2][128 * 32];
  const int tid = threadIdx.x;
  const int wv = tid >> 6, lane = tid & 63;
  const int g = lane >> 4, cidx = lane & 15;
  const int wr = wv >> 1, wc = wv & 1;

  const int nwg = (int)gridDim.x;
  const int q = nwg >> 3, r = nwg & 7;
  const int xcd = (int)blockIdx.x & 7, bidx = (int)blockIdx.x >> 3;
  int wg = (xcd < r ? xcd * (q + 1) : r * (q + 1) + (xcd - r) * q) + bidx;
  const int tpb = Mt * Nt;
  const int b = wg / tpb;
  const int rem = wg % tpb;
  const int mt = rem % Mt, nt = rem / Mt;
  const long m0 = (long)mt * 128, n0 = (long)nt * 128;

  const _Float16* Ab = A + b * Astr + m0 * K;
  const _Float16* Bb = B + b * Bstr + n0 * K;
  const int nkt = (int)(K >> 5);

  const int srow = lane >> 2;
  const int sgr  = (lane & 3) ^ ((lane >> 3) & 3);

  auto stage = [&](int buf, int kt) {
#pragma unroll
    for (int l = 0; l < 2; ++l) {
      const int rbase = wv * 32 + l * 16;
      const long koff = (long)kt * 32 + sgr * 8;
      gload_lds16(Ab + (long)(rbase + srow) * K + koff, &lds[buf][0][rbase * 32]);
      gload_lds16(Bb + (long)(rbase + srow) * K + koff, &lds[buf][1][rbase * 32]);
    }
  };
  const int gr = (g ^ ((cidx >> 1) & 3)) * 8;

  f32x4 acc[4][4] = {};
  stage(0, 0);
  __syncthreads();
  for (int kt = 0; kt < nkt; ++kt) {
    const int cur = kt & 1;
    if (kt + 1 < nkt) stage(cur ^ 1, kt + 1);
    half8 af[4], bf[4];
#pragma unroll
    for (int m = 0; m < 4; ++m)
      af[m] = *(const half8*)&lds[cur][0][(wr * 64 + m * 16 + cidx) * 32 + gr];
#pragma unroll
    for (int n = 0; n < 4; ++n)
      bf[n] = *(const half8*)&lds[cur][1][(wc * 64 + n * 16 + cidx) * 32 + gr];
#pragma unroll
    for (int m = 0; m < 4; ++m)
#pragma unroll
      for (int n = 0; n < 4; ++n)
        acc[m][n] = MFMA_F16(af[m], bf[n], acc[m][n]);
    __syncthreads();
  }

  float bv[4] = {0.f, 0.f, 0.f, 0.f};
  if (bias) {
#pragma unroll
    for (int n = 0; n < 4; ++n) bv[n] = bias[n0 + wc * 64 + n * 16 + cidx];
  }
  if constexpr (OUT_F32) {
    float* C = (float*)Cv + b * Cstr;
#pragma unroll
    for (int m = 0; m < 4; ++m)
#pragma unroll
      for (int rr = 0; rr < 4; ++rr) {
        const long row = m0 + wr * 64 + m * 16 + g * 4 + rr;
        if (row < Areal) {
#pragma unroll
          for (int n = 0; n < 4; ++n)
            C[row * N + n0 + wc * 64 + n * 16 + cidx] = acc[m][n][rr] + bv[n];
        }
      }
  } else {
    _Float16* C = (_Float16*)Cv + b * Cstr;
#pragma unroll
    for (int m = 0; m < 4; ++m)
#pragma unroll
      for (int rr = 0; rr < 4; ++rr) {
        const long row = m0 + wr * 64 + m * 16 + g * 4 + rr;
        if (row < Areal) {
#pragma unroll
          for (int n = 0; n < 4; ++n)
            C[row * N + n0 + wc * 64 + n * 16 + cidx] = (_Float16)acc[m][n][rr];
        }
      }
  }
}

// ==================== heads: S/norms from QG, softmax, WeffT. One block per (b,h) ====================
// S = T1.Wk^T, qn = diag(T1.Wq^T), kn = diag(T3.Wk^T) with T1/T3 = QG_b rows (q/k bands).
__global__ __launch_bounds__(256)
void k_heads(const _Float16* __restrict__ QG, const _Float16* __restrict__ w16,
             const _Float16* __restrict__ wvT, const float* __restrict__ temperature,
             _Float16* __restrict__ weffT)
{
  const int b = blockIdx.x >> 4, h = blockIdx.x & 15;
  const int tid = threadIdx.x;
  const int w = tid >> 6, lane = tid & 63;
  const int g = lane >> 4, c = lane & 15;

  __shared__ float red[4][48 * 48];
  __shared__ float redss[4][2][48];
  __shared__ float inv[2][48];
  __shared__ _Float16 Pb[48 * 64];

  const _Float16* QGq = QG + (long)b * 1179648 + (long)(h * 48) * 768;
  const _Float16* QGk = QGq + 768L * 768;
  const _Float16* Wq  = w16 + (long)(h * 48) * 768;
  const _Float16* Wk  = w16 + (long)(768 + h * 48) * 768;

  f32x4 aS[3][3] = {};
  f32x4 aq[3] = {};
  f32x4 ak[3] = {};
  for (int ks = w * 6; ks < w * 6 + 6; ++ks) {
    const int k0 = ks * 32 + g * 8;
    half8 t1[3], t3[3], wqf[3], wkf[3];
#pragma unroll
    for (int m = 0; m < 3; ++m) {
      const long ro = (long)(m * 16 + c) * 768 + k0;
      t1[m]  = *(const half8*)(QGq + ro);
      t3[m]  = *(const half8*)(QGk + ro);
      wqf[m] = *(const half8*)(Wq + ro);
      wkf[m] = *(const half8*)(Wk + ro);
    }
#pragma unroll
    for (int m = 0; m < 3; ++m) {
      aq[m] = MFMA_F16(t1[m], wqf[m], aq[m]);
      ak[m] = MFMA_F16(t3[m], wkf[m], ak[m]);
#pragma unroll
      for (int n = 0; n < 3; ++n)
        aS[m][n] = MFMA_F16(t1[m], wkf[n], aS[m][n]);
    }
  }

#pragma unroll
  for (int m = 0; m < 3; ++m) {
#pragma unroll
    for (int n = 0; n < 3; ++n)
#pragma unroll
      for (int rr = 0; rr < 4; ++rr)
        red[w][(m * 16 + g * 4 + rr) * 48 + n * 16 + c] = aS[m][n][rr];
#pragma unroll
    for (int rr = 0; rr < 4; ++rr)
      if (c == g * 4 + rr) {
        redss[w][0][m * 16 + c] = aq[m][rr];
        redss[w][1][m * 16 + c] = ak[m][rr];
      }
  }
  __syncthreads();

  if (tid < 96) {
    const int is_k = tid / 48, d = tid % 48;
    const float s = redss[0][is_k][d] + redss[1][is_k][d] + redss[2][is_k][d] + redss[3][is_k][d];
    inv[is_k][d] = 1.0f / fmaxf(sqrtf(s), 1e-12f);
  }
  __syncthreads();

  if (tid < 48) {
    const int d = tid;
    const float iq = inv[0][d] * temperature[h];
    float rowv[48];
    float mx = -3.0e38f;
#pragma unroll
    for (int e = 0; e < 48; ++e) {
      const int idx = d * 48 + e;
      float t = (red[0][idx] + red[1][idx] + red[2][idx] + red[3][idx]) * iq * inv[1][e];
      rowv[e] = t;
      mx = fmaxf(mx, t);
    }
    float sum = 0.f;
#pragma unroll
    for (int e = 0; e < 48; ++e) {
      const float pv = __expf(rowv[e] - mx);
      rowv[e] = pv;
      sum += pv;
    }
    const float is = 1.0f / sum;
#pragma unroll
    for (int e = 0; e < 48; ++e)
      Pb[d * 64 + e] = (_Float16)(rowv[e] * is);
#pragma unroll
    for (int e = 48; e < 64; ++e)
      Pb[d * 64 + e] = (_Float16)0.f;
  }
  __syncthreads();

  // WeffT_b[f][h*48+d] = sum_e wvT[h][f][e] P[d][e]
  half8 pf[3][2];
#pragma unroll
  for (int nf = 0; nf < 3; ++nf)
#pragma unroll
    for (int ks = 0; ks < 2; ++ks)
      pf[nf][ks] = *(const half8*)&Pb[(nf * 16 + c) * 64 + ks * 32 + g * 8];

  const _Float16* wvh = wvT + (long)h * 768 * 64;
  _Float16* wout = weffT + (long)b * 589824 + h * 48;

  for (int m = 0; m < 12; ++m) {
    const int f0 = w * 192 + m * 16;
    half8 va[2];
#pragma unroll
    for (int ks = 0; ks < 2; ++ks)
      va[ks] = *(const half8*)&wvh[(long)(f0 + c) * 64 + ks * 32 + g * 8];
    f32x4 a3[3] = {};
#pragma unroll
    for (int ks = 0; ks < 2; ++ks)
#pragma unroll
      for (int nf = 0; nf < 3; ++nf)
        a3[nf] = MFMA_F16(va[ks], pf[nf][ks], a3[nf]);
#pragma unroll
    for (int nf = 0; nf < 3; ++nf)
#pragma unroll
      for (int rr = 0; rr < 4; ++rr)
        wout[(long)(f0 + g * 4 + rr) * 768 + nf * 16 + c] = (_Float16)a3[nf][rr];
  }
}

// -------------------- launch --------------------
extern "C" void kernel_launch(void* const* d_in, const int* in_sizes, int n_in,
                              void* d_out, int out_size, void* d_ws, size_t ws_size,
                              hipStream_t stream)
{
  (void)in_sizes; (void)n_in; (void)out_size; (void)ws_size;
  const float* x      = (const float*)d_in[0];
  const float* w_qkv  = (const float*)d_in[1];
  const float* temp   = (const float*)d_in[2];
  const float* w_proj = (const float*)d_in[3];
  const float* b_proj = (const float*)d_in[4];
  float* out = (float*)d_out;

  // ws layout (bytes), total 254,803,968:
  //   [0)          x16   : 77,070,336   [50176][768]
  //   [77070336)   xT    : 77,070,336   [16][768][3136]
  //   [154140672)  G     : 18,874,368   [16][768][768]
  //   [173015040)  QG    : 37,748,736   [16][1536][768]
  //   [210763776)  weffT : 18,874,368   [16][768 f][768 c]
  //   [229638144)  wfin  : 18,874,368   [16][768 o][768 f]
  //   [248512512)  w16   : 3,538,944
  //   [252051456)  wp16  : 1,179,648
  //   [253231104)  wvT   : 1,572,864
  char* ws = (char*)d_ws;
  _Float16* x16   = (_Float16*)(ws);
  _Float16* xT    = (_Float16*)(ws + 77070336L);
  _Float16* G     = (_Float16*)(ws + 154140672L);
  _Float16* QG    = (_Float16*)(ws + 173015040L);
  _Float16* weffT = (_Float16*)(ws + 210763776L);
  _Float16* wfin  = (_Float16*)(ws + 229638144L);
  _Float16* w16   = (_Float16*)(ws + 248512512L);
  _Float16* wp16  = (_Float16*)(ws + 252051456L);
  _Float16* wvT   = (_Float16*)(ws + 253231104L);

  k_cvtw<<<768, 256, 0, stream>>>(w_qkv, w_proj, w16, wp16, wvT);
  k_cvtx<<<9408, 256, 0, stream>>>(x, x16, xT);
  // G_b = xT_b . xT_b^T (symmetric)
  k_gram<<<336, 256, 0, stream>>>(xT, G);
  // QG_b = w16[0:1536] . G_b   (G symmetric -> bt form ok)
  k_g128<false><<<1152, 256, 0, stream>>>(w16, G, QG, nullptr,
                                          12, 6, 1536, 0, 589824, 1179648, 768, 768);
  // per (b,h): S, norms, softmax, WeffT
  k_heads<<<256, 256, 0, stream>>>(QG, w16, wvT, temp, weffT);
  // wfin_b = Wp . Weff_b
  k_g128<false><<<576, 256, 0, stream>>>(wp16, weffT, wfin, nullptr,
                                         6, 6, 768, 0, 589824, 589824, 768, 768);
  // out_b[t][o] = x16_b[t,:] . wfin_b[o,:] + bias  (fp32, M-tail masked)
  k_g128<true><<<2400, 256, 0, stream>>>(x16, wfin, out, b_proj,
                                         25, 6, 3136, 3136L * 768, 589824, 3136L * 768,
                                         768, 768);
}